// Round 1
// 490.744 us; speedup vs baseline: 1.1510x; 1.1510x over previous
//
#include <hip/hip_runtime.h>
#include <math.h>

#define N_NODES 100000
#define N_EDGES 3200000
#define D_IN    256
#define D_OUT   128
#define ALPHA   0.2f

// counting-sort chunking: per-block LDS-privatized histogram
#define NB_HIST 125                    // chunks == hist blocks
#define CHUNK   (N_EDGES / NB_HIST)    // 25600 edges per chunk (25600 % 512 == 0)
#define HWORDS  (N_NODES / 4)          // 25000 packed u8x4 bins = 100 KB LDS

typedef short bf8_t  __attribute__((ext_vector_type(8)));   // 8 bf16 (MFMA A/B frag)
typedef float f4_t   __attribute__((ext_vector_type(4)));   // 4 f32  (MFMA C/D frag)

// round-to-nearest-even f32 -> bf16
__device__ __forceinline__ unsigned int f2bf(float x) {
    unsigned int u = __float_as_uint(x);
    return (u + 0x7fffu + ((u >> 16) & 1u)) >> 16;
}
__device__ __forceinline__ unsigned int packbf(float lo, float hi) {
    return f2bf(lo) | (f2bf(hi) << 16);
}
__device__ __forceinline__ float bflo(unsigned int v) { return __uint_as_float(v << 16); }
__device__ __forceinline__ float bfhi(unsigned int v) { return __uint_as_float(v & 0xffff0000u); }

// ---------- WT: W[k][n] f32 -> WT[n][k] bf16 (64 KB, done once per launch) ----------
__global__ void wt_kernel(const float* __restrict__ W, short* __restrict__ WT) {
    int i = blockIdx.x * 256 + threadIdx.x;   // 32768
    int n = i >> 8, k = i & 255;
    WT[i] = (short)f2bf(W[k * 128 + n]);
}

// ---------- GEMM via bf16 MFMA: seq = feat @ W + fused f1/f2 epilogue ----------
// Block: 256 thr = 4 waves; wave handles 16 rows x 128 cols. Block = 64 rows.
// feat tile staged f32->bf16 into LDS ([64][264] shorts, +16B row pad -> fragment
// reads are bank-bandwidth-optimal). B-frags read straight from global WT (16B
// contiguous per lane, L1/L2-resident 64 KB). mfma_f32_16x16x32_bf16:
//   A[m=lane&15][k=quad*8+j], B[k=quad*8+j][n=lane&15], C col=lane&15 row=quad*4+reg.
__global__ __launch_bounds__(256) void gemm_kernel(const float* __restrict__ feat,
                                                   const short* __restrict__ WT,
                                                   const float* __restrict__ al_w,
                                                   const float* __restrict__ al_b,
                                                   const float* __restrict__ ar_w,
                                                   const float* __restrict__ ar_b,
                                                   unsigned int* __restrict__ seqb,
                                                   float* __restrict__ f1,
                                                   float* __restrict__ f2) {
    __shared__ char ldsA[64 * 528];   // 33.8 KB  (row stride 528 B = 264 bf16)
    const int tid = threadIdx.x;
    const int tb  = blockIdx.x * 64;

    // ---- stage feat[tb..tb+63][0..255] as bf16 (clamp rows past N; stores guarded) ----
#pragma unroll
    for (int i = 0; i < 16; i++) {
        int idx = i * 256 + tid;          // over 4096 float4
        int r   = idx >> 6;               // tile row 0..63
        int c4  = idx & 63;               // float4 index 0..63
        int gr  = tb + r; if (gr >= N_NODES) gr = N_NODES - 1;
        float4 v = ((const float4*)feat)[(size_t)gr * 64 + c4];
        *(uint2*)(ldsA + r * 528 + c4 * 8) =
            make_uint2(packbf(v.x, v.y), packbf(v.z, v.w));
    }
    __syncthreads();

    const int w    = tid >> 6;      // wave 0..3 -> rows tb + w*16 ..
    const int lane = tid & 63;
    const int m    = lane & 15;     // A row / B col within tile
    const int q    = lane >> 4;     // quad -> k offset q*8, C rows q*4..q*4+3

    const char*  aptr  = ldsA + (w * 16 + m) * 528 + q * 16;
    const short* bbase = WT + m * 256 + q * 8;   // + nt*16*256 + kc*32

    f4_t acc[8];
#pragma unroll
    for (int nt = 0; nt < 8; nt++) acc[nt] = (f4_t)(0.f);

#pragma unroll
    for (int kc = 0; kc < 8; kc++) {
        bf8_t a = *(const bf8_t*)(aptr + kc * 64);
#pragma unroll
        for (int nt = 0; nt < 8; nt++) {
            bf8_t b = *(const bf8_t*)(bbase + nt * 4096 + kc * 32);
            acc[nt] = __builtin_amdgcn_mfma_f32_16x16x32_bf16(a, b, acc[nt], 0, 0, 0);
        }
    }

    // ---- epilogue 1: seqb packed bf16x2 (pair adjacent cols via shfl_xor(1)) ----
    const int node_base = tb + w * 16 + q * 4;
#pragma unroll
    for (int nt = 0; nt < 8; nt++) {
#pragma unroll
        for (int j = 0; j < 4; j++) {
            float own   = acc[nt][j];
            float other = __shfl_xor(own, 1);
            int node = node_base + j;
            if (!(lane & 1) && node < N_NODES)
                seqb[(size_t)node * 64 + nt * 8 + (m >> 1)] = packbf(own, other);
        }
    }

    // ---- epilogue 2: f1/f2 = seq . al_w / ar_w (reduce over cols = lanes m) ----
    float p1[4] = {0.f, 0.f, 0.f, 0.f}, p2[4] = {0.f, 0.f, 0.f, 0.f};
#pragma unroll
    for (int nt = 0; nt < 8; nt++) {
        float av = al_w[nt * 16 + m];
        float rv = ar_w[nt * 16 + m];
#pragma unroll
        for (int j = 0; j < 4; j++) {
            p1[j] += acc[nt][j] * av;
            p2[j] += acc[nt][j] * rv;
        }
    }
#pragma unroll
    for (int j = 0; j < 4; j++) {
#pragma unroll
        for (int mk = 1; mk < 16; mk <<= 1) {
            p1[j] += __shfl_xor(p1[j], mk);
            p2[j] += __shfl_xor(p2[j], mk);
        }
    }
    if (m == 0) {
        float alb = al_b[0], arb = ar_b[0];
#pragma unroll
        for (int j = 0; j < 4; j++) {
            int node = node_base + j;
            if (node < N_NODES) {
                f1[node] = p1[j] + alb;
                f2[node] = p2[j] + arb;
            }
        }
    }
}

// ---------- chunk-privatized histogram + within-chunk rank (NO global atomics) ----------
// Each block owns one 25600-edge chunk and a full 100K-bin histogram in LDS,
// packed 4 u8 counters per u32 word (degrees are <=255 so bytes never carry).
// LDS atomicAdd's return value IS the edge's within-chunk rank. The per-chunk
// histogram goes to global for the cross-chunk prefix (scanb_kernel).
__global__ __launch_bounds__(512) void hist_kernel(const int* __restrict__ row,
                                                   unsigned char* __restrict__ localrank,
                                                   unsigned int* __restrict__ histpk) {
    __shared__ unsigned int h[HWORDS];    // 100 KB
    const int tid = threadIdx.x;
    for (int i = tid; i < HWORDS; i += 512) h[i] = 0u;
    __syncthreads();

    const int base = blockIdx.x * CHUNK;
#pragma unroll 5
    for (int it = 0; it < CHUNK / 512; it++) {
        int e = base + it * 512 + tid;
        int r = row[e];
        unsigned int sh  = (unsigned int)(r & 3) * 8u;
        unsigned int old = atomicAdd(&h[r >> 2], 1u << sh);
        localrank[e] = (unsigned char)((old >> sh) & 0xffu);
    }
    __syncthreads();

    unsigned int* dst = histpk + (size_t)blockIdx.x * HWORDS;
    for (int i = tid; i < HWORDS; i += 512) dst[i] = h[i];
}

// ---------- cross-chunk exclusive prefix per row + total degree ----------
// Thread owns 4 rows (one packed word). Packed byte-adds cannot carry since the
// running total per row is the final degree (<=255).
__global__ __launch_bounds__(256) void scanb_kernel(const unsigned int* __restrict__ histpk,
                                                    unsigned int* __restrict__ blockpre,
                                                    uint4* __restrict__ cnt4) {
    int w = blockIdx.x * 256 + threadIdx.x;
    if (w >= HWORDS) return;
    unsigned int run = 0u;
    for (int b = 0; b < NB_HIST; b++) {
        unsigned int hv = histpk[(size_t)b * HWORDS + w];
        blockpre[(size_t)b * HWORDS + w] = run;
        run += hv;
    }
    cnt4[w] = make_uint4(run & 0xffu, (run >> 8) & 0xffu,
                         (run >> 16) & 0xffu, run >> 24);
}

// ---------- exclusive scan of degrees -> CSR row offsets ----------
__global__ void scan1(const unsigned int* __restrict__ cnt,
                      unsigned int* __restrict__ offs,
                      unsigned int* __restrict__ bsums) {
    __shared__ unsigned int s[256];
    int t = threadIdx.x;
    int i = blockIdx.x * 256 + t;
    unsigned int v = (i < N_NODES) ? cnt[i] : 0u;
    s[t] = v; __syncthreads();
    for (int d = 1; d < 256; d <<= 1) {
        unsigned int x = (t >= d) ? s[t - d] : 0u;
        __syncthreads();
        s[t] += x;
        __syncthreads();
    }
    if (i < N_NODES) offs[i] = s[t] - v;
    if (t == 255) bsums[blockIdx.x] = s[255];
}

__global__ void scan2(const unsigned int* __restrict__ bsums,
                      unsigned int* __restrict__ bexcl, int nb) {
    __shared__ unsigned int s[512];
    int t = threadIdx.x;
    unsigned int v = (t < nb) ? bsums[t] : 0u;
    s[t] = v; __syncthreads();
    for (int d = 1; d < 512; d <<= 1) {
        unsigned int x = (t >= d) ? s[t - d] : 0u;
        __syncthreads();
        s[t] += x;
        __syncthreads();
    }
    if (t < nb) bexcl[t] = s[t] - v;
}

__global__ void scan3(unsigned int* __restrict__ offs,
                      const unsigned int* __restrict__ bexcl) {
    int i = blockIdx.x * 256 + threadIdx.x;
    if (i < N_NODES) offs[i] += bexcl[blockIdx.x];
}

// ---------- single-pass CSR scatter (no atomics, no segment passes) ----------
// position = global row offset + (#same-row edges in earlier chunks) + within-chunk rank
__global__ __launch_bounds__(256) void scatter_kernel(const int* __restrict__ row,
                                                      const int* __restrict__ col,
                                                      const unsigned char* __restrict__ localrank,
                                                      const unsigned char* __restrict__ blockpre_u8,
                                                      const unsigned int* __restrict__ offs,
                                                      int* __restrict__ sorted_c) {
    int e = blockIdx.x * 256 + threadIdx.x;
    int b = (blockIdx.x * 256) / CHUNK;          // uniform per block (CHUNK % 256 == 0)
    int r = row[e];
    unsigned int p = offs[r]
                   + (unsigned int)blockpre_u8[(size_t)b * N_NODES + r]
                   + (unsigned int)localrank[e];
    sorted_c[p] = col[e];
}

// ---------- row aggregate ----------
__global__ __launch_bounds__(256) void row_kernel(const uint2* __restrict__ seqb2,
                                                  const int* __restrict__ sorted_c,
                                                  const unsigned int* __restrict__ offs,
                                                  const unsigned int* __restrict__ cnt,
                                                  const float* __restrict__ f1,
                                                  const float* __restrict__ f2,
                                                  const float* __restrict__ bias,
                                                  float* __restrict__ out) {
    int wid  = (blockIdx.x * 256 + threadIdx.x) >> 6;   // row
    int lane = threadIdx.x & 63;
    int half = lane >> 5;
    int j2   = lane & 31;       // cols 4*j2 .. 4*j2+3
    if (wid >= N_NODES) return;
    unsigned int start = offs[wid];
    unsigned int deg   = cnt[wid];
    const int* sc = sorted_c + start;
    float f1r = f1[wid];

    float a0 = 0.f, a1 = 0.f, a2 = 0.f, a3 = 0.f, ss = 0.f;
    unsigned int k = 0;
    for (; k + 8 <= deg; k += 8) {
        int c0 = sc[k + 0 + half];
        int c1 = sc[k + 2 + half];
        int c2 = sc[k + 4 + half];
        int c3 = sc[k + 6 + half];
        uint2 v0 = seqb2[(size_t)c0 * 32 + j2];
        uint2 v1 = seqb2[(size_t)c1 * 32 + j2];
        uint2 v2 = seqb2[(size_t)c2 * 32 + j2];
        uint2 v3 = seqb2[(size_t)c3 * 32 + j2];
        float t0 = f1r + f2[c0], t1 = f1r + f2[c1];
        float t2 = f1r + f2[c2], t3 = f1r + f2[c3];
        float w0 = __expf(t0 > 0.f ? t0 : ALPHA * t0);
        float w1 = __expf(t1 > 0.f ? t1 : ALPHA * t1);
        float w2 = __expf(t2 > 0.f ? t2 : ALPHA * t2);
        float w3 = __expf(t3 > 0.f ? t3 : ALPHA * t3);
        a0 += w0 * bflo(v0.x); a1 += w0 * bfhi(v0.x); a2 += w0 * bflo(v0.y); a3 += w0 * bfhi(v0.y);
        a0 += w1 * bflo(v1.x); a1 += w1 * bfhi(v1.x); a2 += w1 * bflo(v1.y); a3 += w1 * bfhi(v1.y);
        a0 += w2 * bflo(v2.x); a1 += w2 * bfhi(v2.x); a2 += w2 * bflo(v2.y); a3 += w2 * bfhi(v2.y);
        a0 += w3 * bflo(v3.x); a1 += w3 * bfhi(v3.x); a2 += w3 * bflo(v3.y); a3 += w3 * bfhi(v3.y);
        ss += w0 + w1 + w2 + w3;
    }
    for (; k + 2 <= deg; k += 2) {       // pairs: one edge per half
        int c0 = sc[k + half];
        uint2 v0 = seqb2[(size_t)c0 * 32 + j2];
        float t0 = f1r + f2[c0];
        float w0 = __expf(t0 > 0.f ? t0 : ALPHA * t0);
        a0 += w0 * bflo(v0.x); a1 += w0 * bfhi(v0.x); a2 += w0 * bflo(v0.y); a3 += w0 * bfhi(v0.y);
        ss += w0;
    }
    if (k < deg && half == 0) {          // final odd edge: half 0 only
        int c0 = sc[k];
        uint2 v0 = seqb2[(size_t)c0 * 32 + j2];
        float t0 = f1r + f2[c0];
        float w0 = __expf(t0 > 0.f ? t0 : ALPHA * t0);
        a0 += w0 * bflo(v0.x); a1 += w0 * bfhi(v0.x); a2 += w0 * bflo(v0.y); a3 += w0 * bfhi(v0.y);
        ss += w0;
    }
    a0 += __shfl_xor(a0, 32);
    a1 += __shfl_xor(a1, 32);
    a2 += __shfl_xor(a2, 32);
    a3 += __shfl_xor(a3, 32);
    ss += __shfl_xor(ss, 32);

    if (half == 0) {
        float inv = (deg > 0) ? 1.f / ss : 0.f;   // empty row -> bias only
        float4 b4 = ((const float4*)bias)[j2];
        ((float4*)(out + (size_t)wid * D_OUT))[j2] =
            make_float4(a0 * inv + b4.x, a1 * inv + b4.y, a2 * inv + b4.z, a3 * inv + b4.w);
    }
}

extern "C" void kernel_launch(void* const* d_in, const int* in_sizes, int n_in,
                              void* d_out, int out_size, void* d_ws, size_t ws_size,
                              hipStream_t stream) {
    const float* feat = (const float*)d_in[0];
    const int*   row  = (const int*)d_in[1];
    const int*   col  = (const int*)d_in[2];
    const float* W    = (const float*)d_in[3];
    const float* al_w = (const float*)d_in[4];
    const float* al_b = (const float*)d_in[5];
    const float* ar_w = (const float*)d_in[6];
    const float* ar_b = (const float*)d_in[7];
    const float* bias = (const float*)d_in[8];
    float* out = (float*)d_out;

    char* ws = (char*)d_ws;
    size_t off = 0;
    auto carve = [&](size_t bytes) -> void* {
        off = (off + 255) & ~(size_t)255;
        void* p = ws + off;
        off += bytes;
        return p;
    };
    unsigned int* seqb     = (unsigned int*)carve((size_t)N_NODES * 64 * 4);  // bf16x2 packed
    float*        f1       = (float*)       carve((size_t)N_NODES * 4);
    float*        f2       = (float*)       carve((size_t)N_NODES * 4);
    unsigned int* cnt      = (unsigned int*)carve((size_t)N_NODES * 4);
    unsigned int* offs     = (unsigned int*)carve((size_t)N_NODES * 4);
    unsigned int* bsums    = (unsigned int*)carve(1024 * 4);
    unsigned int* bexcl    = (unsigned int*)carve(1024 * 4);
    short*        WT       = (short*)       carve((size_t)D_IN * D_OUT * 2);  // bf16 W^T
    unsigned char* localrank = (unsigned char*)carve((size_t)N_EDGES);
    unsigned int* blockpre = (unsigned int*)carve((size_t)NB_HIST * HWORDS * 4);  // 12.5 MB
    // histpk (12.5 MB) is dead after scanb_kernel; sorted_c (12.8 MB) is written
    // only afterwards (stream-ordered) -> alias them in one region.
    int*          sorted_c = (int*)         carve((size_t)N_EDGES * 4);
    unsigned int* histpk   = (unsigned int*)sorted_c;
    (void)ws_size; (void)in_sizes; (void)n_in; (void)out_size;

    const int nb_nodes = (N_NODES + 255) / 256;     // 391
    const int nb_gemm  = (N_NODES + 63) / 64;       // 1563 (last block guarded)
    const int nb_scanb = (HWORDS + 255) / 256;      // 98
    const int nb_scat  = N_EDGES / 256;             // 12500 exact
    const int nb_row   = N_NODES / 4;               // 25000 exact (4 waves/block)

    wt_kernel<<<(D_IN * D_OUT) / 256, 256, 0, stream>>>(W, WT);
    gemm_kernel<<<nb_gemm, 256, 0, stream>>>(feat, WT, al_w, al_b, ar_w, ar_b, seqb, f1, f2);
    hist_kernel<<<NB_HIST, 512, 0, stream>>>(row, localrank, histpk);
    scanb_kernel<<<nb_scanb, 256, 0, stream>>>(histpk, blockpre, (uint4*)cnt);
    scan1<<<nb_nodes, 256, 0, stream>>>(cnt, offs, bsums);
    scan2<<<1, 512, 0, stream>>>(bsums, bexcl, nb_nodes);
    scan3<<<nb_nodes, 256, 0, stream>>>(offs, bexcl);
    scatter_kernel<<<nb_scat, 256, 0, stream>>>(row, col, localrank,
                                                (const unsigned char*)blockpre, offs, sorted_c);
    row_kernel<<<nb_row, 256, 0, stream>>>((const uint2*)seqb, sorted_c, offs, cnt, f1, f2, bias, out);
}

// Round 2
// 477.082 us; speedup vs baseline: 1.1840x; 1.0286x over previous
//
#include <hip/hip_runtime.h>
#include <math.h>

#define N_NODES 100000
#define N_EDGES 3200000
#define D_IN    256
#define D_OUT   128
#define ALPHA   0.2f

// counting-sort chunking: per-block LDS-privatized histogram
#define NB_HIST 125                    // chunks == hist blocks
#define CHUNK   (N_EDGES / NB_HIST)    // 25600 edges per chunk (25600 % 1024 == 0)
#define HWORDS  (N_NODES / 4)          // 25000 packed u8x4 bins = 100 KB LDS

typedef short bf8_t  __attribute__((ext_vector_type(8)));   // 8 bf16 (MFMA A/B frag)
typedef float f4_t   __attribute__((ext_vector_type(4)));   // 4 f32  (MFMA C/D frag)

// round-to-nearest-even f32 -> bf16
__device__ __forceinline__ unsigned int f2bf(float x) {
    unsigned int u = __float_as_uint(x);
    return (u + 0x7fffu + ((u >> 16) & 1u)) >> 16;
}
__device__ __forceinline__ unsigned int packbf(float lo, float hi) {
    return f2bf(lo) | (f2bf(hi) << 16);
}
__device__ __forceinline__ float bflo(unsigned int v) { return __uint_as_float(v << 16); }
__device__ __forceinline__ float bfhi(unsigned int v) { return __uint_as_float(v & 0xffff0000u); }

// ---------- WT: W[k][n] f32 -> WT[n][k] bf16 (64 KB, done once per launch) ----------
__global__ void wt_kernel(const float* __restrict__ W, short* __restrict__ WT) {
    int i = blockIdx.x * 256 + threadIdx.x;   // 32768
    int n = i >> 8, k = i & 255;
    WT[i] = (short)f2bf(W[k * 128 + n]);
}

// ---------- GEMM via bf16 MFMA: seq = feat @ W + fused f1/f2 epilogue ----------
// Block: 256 thr = 4 waves; wave handles 16 rows x 128 cols. Block = 64 rows.
// feat tile staged f32->bf16 into LDS ([64][264] shorts, +16B row pad -> fragment
// reads are bank-bandwidth-optimal). B-frags read straight from global WT (16B
// contiguous per lane, L1/L2-resident 64 KB). mfma_f32_16x16x32_bf16:
//   A[m=lane&15][k=quad*8+j], B[k=quad*8+j][n=lane&15], C col=lane&15 row=quad*4+reg.
__global__ __launch_bounds__(256) void gemm_kernel(const float* __restrict__ feat,
                                                   const short* __restrict__ WT,
                                                   const float* __restrict__ al_w,
                                                   const float* __restrict__ al_b,
                                                   const float* __restrict__ ar_w,
                                                   const float* __restrict__ ar_b,
                                                   unsigned int* __restrict__ seqb,
                                                   float* __restrict__ f1,
                                                   float* __restrict__ f2) {
    __shared__ char ldsA[64 * 528];   // 33.8 KB  (row stride 528 B = 264 bf16)
    const int tid = threadIdx.x;
    const int tb  = blockIdx.x * 64;

    // ---- stage feat[tb..tb+63][0..255] as bf16 (clamp rows past N; stores guarded) ----
#pragma unroll
    for (int i = 0; i < 16; i++) {
        int idx = i * 256 + tid;          // over 4096 float4
        int r   = idx >> 6;               // tile row 0..63
        int c4  = idx & 63;               // float4 index 0..63
        int gr  = tb + r; if (gr >= N_NODES) gr = N_NODES - 1;
        float4 v = ((const float4*)feat)[(size_t)gr * 64 + c4];
        *(uint2*)(ldsA + r * 528 + c4 * 8) =
            make_uint2(packbf(v.x, v.y), packbf(v.z, v.w));
    }
    __syncthreads();

    const int w    = tid >> 6;      // wave 0..3 -> rows tb + w*16 ..
    const int lane = tid & 63;
    const int m    = lane & 15;     // A row / B col within tile
    const int q    = lane >> 4;     // quad -> k offset q*8, C rows q*4..q*4+3

    const char*  aptr  = ldsA + (w * 16 + m) * 528 + q * 16;
    const short* bbase = WT + m * 256 + q * 8;   // + nt*16*256 + kc*32

    f4_t acc[8];
#pragma unroll
    for (int nt = 0; nt < 8; nt++) acc[nt] = (f4_t)(0.f);

#pragma unroll
    for (int kc = 0; kc < 8; kc++) {
        bf8_t a = *(const bf8_t*)(aptr + kc * 64);
#pragma unroll
        for (int nt = 0; nt < 8; nt++) {
            bf8_t b = *(const bf8_t*)(bbase + nt * 4096 + kc * 32);
            acc[nt] = __builtin_amdgcn_mfma_f32_16x16x32_bf16(a, b, acc[nt], 0, 0, 0);
        }
    }

    // ---- epilogue 1: seqb packed bf16x2 (pair adjacent cols via shfl_xor(1)) ----
    const int node_base = tb + w * 16 + q * 4;
#pragma unroll
    for (int nt = 0; nt < 8; nt++) {
#pragma unroll
        for (int j = 0; j < 4; j++) {
            float own   = acc[nt][j];
            float other = __shfl_xor(own, 1);
            int node = node_base + j;
            if (!(lane & 1) && node < N_NODES)
                seqb[(size_t)node * 64 + nt * 8 + (m >> 1)] = packbf(own, other);
        }
    }

    // ---- epilogue 2: f1/f2 = seq . al_w / ar_w (reduce over cols = lanes m) ----
    float p1[4] = {0.f, 0.f, 0.f, 0.f}, p2[4] = {0.f, 0.f, 0.f, 0.f};
#pragma unroll
    for (int nt = 0; nt < 8; nt++) {
        float av = al_w[nt * 16 + m];
        float rv = ar_w[nt * 16 + m];
#pragma unroll
        for (int j = 0; j < 4; j++) {
            p1[j] += acc[nt][j] * av;
            p2[j] += acc[nt][j] * rv;
        }
    }
#pragma unroll
    for (int j = 0; j < 4; j++) {
#pragma unroll
        for (int mk = 1; mk < 16; mk <<= 1) {
            p1[j] += __shfl_xor(p1[j], mk);
            p2[j] += __shfl_xor(p2[j], mk);
        }
    }
    if (m == 0) {
        float alb = al_b[0], arb = ar_b[0];
#pragma unroll
        for (int j = 0; j < 4; j++) {
            int node = node_base + j;
            if (node < N_NODES) {
                f1[node] = p1[j] + alb;
                f2[node] = p2[j] + arb;
            }
        }
    }
}

// ---------- chunk-privatized histogram + within-chunk rank (NO global atomics) ----------
// Each block owns one 25600-edge chunk and a full 100K-bin histogram in LDS,
// packed 4 u8 counters per u32 word (degrees are <=255 so bytes never carry).
// LDS atomicAdd's return value IS the edge's within-chunk rank. 1024 threads:
// only 1 block/CU fits (100 KB LDS), so maximize waves per block (16) for MLP.
__global__ __launch_bounds__(1024) void hist_kernel(const int* __restrict__ row,
                                                    unsigned char* __restrict__ localrank,
                                                    unsigned int* __restrict__ histpk) {
    __shared__ unsigned int h[HWORDS];    // 100 KB
    const int tid = threadIdx.x;
    for (int i = tid; i < HWORDS; i += 1024) h[i] = 0u;
    __syncthreads();

    const int base = blockIdx.x * CHUNK;
#pragma unroll 5
    for (int it = 0; it < CHUNK / 1024; it++) {
        int e = base + it * 1024 + tid;
        int r = row[e];
        unsigned int sh  = (unsigned int)(r & 3) * 8u;
        unsigned int old = atomicAdd(&h[r >> 2], 1u << sh);
        localrank[e] = (unsigned char)((old >> sh) & 0xffu);
    }
    __syncthreads();

    unsigned int* dst = histpk + (size_t)blockIdx.x * HWORDS;
    for (int i = tid; i < HWORDS; i += 1024) dst[i] = h[i];
}

// ---------- cross-chunk exclusive prefix per row + total degree ----------
// Thread owns 4 rows (one packed word). Packed byte-adds cannot carry since the
// running total per row is the final degree (<=255). unroll 5 -> 5 loads in flight
// (grid is only 390 waves; latency hiding must come from ILP).
__global__ __launch_bounds__(256) void scanb_kernel(const unsigned int* __restrict__ histpk,
                                                    unsigned int* __restrict__ blockpre,
                                                    uint4* __restrict__ cnt4) {
    int w = blockIdx.x * 256 + threadIdx.x;
    if (w >= HWORDS) return;
    unsigned int run = 0u;
#pragma unroll 5
    for (int b = 0; b < NB_HIST; b++) {
        unsigned int hv = histpk[(size_t)b * HWORDS + w];
        blockpre[(size_t)b * HWORDS + w] = run;
        run += hv;
    }
    cnt4[w] = make_uint4(run & 0xffu, (run >> 8) & 0xffu,
                         (run >> 16) & 0xffu, run >> 24);
}

// ---------- exclusive scan of degrees -> CSR row offsets ----------
__global__ void scan1(const unsigned int* __restrict__ cnt,
                      unsigned int* __restrict__ offs,
                      unsigned int* __restrict__ bsums) {
    __shared__ unsigned int s[256];
    int t = threadIdx.x;
    int i = blockIdx.x * 256 + t;
    unsigned int v = (i < N_NODES) ? cnt[i] : 0u;
    s[t] = v; __syncthreads();
    for (int d = 1; d < 256; d <<= 1) {
        unsigned int x = (t >= d) ? s[t - d] : 0u;
        __syncthreads();
        s[t] += x;
        __syncthreads();
    }
    if (i < N_NODES) offs[i] = s[t] - v;
    if (t == 255) bsums[blockIdx.x] = s[255];
}

__global__ void scan2(const unsigned int* __restrict__ bsums,
                      unsigned int* __restrict__ bexcl, int nb) {
    __shared__ unsigned int s[512];
    int t = threadIdx.x;
    unsigned int v = (t < nb) ? bsums[t] : 0u;
    s[t] = v; __syncthreads();
    for (int d = 1; d < 512; d <<= 1) {
        unsigned int x = (t >= d) ? s[t - d] : 0u;
        __syncthreads();
        s[t] += x;
        __syncthreads();
    }
    if (t < nb) bexcl[t] = s[t] - v;
}

__global__ void scan3(unsigned int* __restrict__ offs,
                      const unsigned int* __restrict__ bexcl) {
    int i = blockIdx.x * 256 + threadIdx.x;
    if (i < N_NODES) offs[i] += bexcl[blockIdx.x];
}

// ---------- single-pass CSR scatter (no atomics, no segment passes) ----------
// position = global row offset + (#same-row edges in earlier chunks) + within-chunk rank
__global__ __launch_bounds__(256) void scatter_kernel(const int* __restrict__ row,
                                                      const int* __restrict__ col,
                                                      const unsigned char* __restrict__ localrank,
                                                      const unsigned char* __restrict__ blockpre_u8,
                                                      const unsigned int* __restrict__ offs,
                                                      int* __restrict__ sorted_c) {
    int e = blockIdx.x * 256 + threadIdx.x;
    int b = (blockIdx.x * 256) / CHUNK;          // uniform per block (CHUNK % 256 == 0)
    int r = row[e];
    unsigned int p = offs[r]
                   + (unsigned int)blockpre_u8[(size_t)b * N_NODES + r]
                   + (unsigned int)localrank[e];
    sorted_c[p] = col[e];
}

// ---------- row aggregate ----------
// One wave per row. 16 lanes x uint4 (16 B/lane) cover one 256 B seqb row ->
// 4 edge-groups per wave, hand-unrolled x2 (8 edges in flight). Halves load
// instructions / address math / duplicated exp vs the uint2 version.
__global__ __launch_bounds__(256) void row_kernel(const uint4* __restrict__ seqb4,
                                                  const int* __restrict__ sorted_c,
                                                  const unsigned int* __restrict__ offs,
                                                  const unsigned int* __restrict__ cnt,
                                                  const float* __restrict__ f1,
                                                  const float* __restrict__ f2,
                                                  const float* __restrict__ bias,
                                                  float* __restrict__ out) {
    int wid  = (blockIdx.x * 256 + threadIdx.x) >> 6;   // row
    int lane = threadIdx.x & 63;
    int g    = lane >> 4;        // edge group 0..3
    int j4   = lane & 15;        // uint4 index within row: cols 8*j4 .. 8*j4+7
    if (wid >= N_NODES) return;
    unsigned int start = offs[wid];
    unsigned int deg   = cnt[wid];
    const int* sc = sorted_c + start;
    float f1r = f1[wid];

    float a0 = 0.f, a1 = 0.f, a2 = 0.f, a3 = 0.f;
    float a4 = 0.f, a5 = 0.f, a6 = 0.f, a7 = 0.f, ss = 0.f;

    unsigned int k = 0;
    for (; k + 8 <= deg; k += 8) {           // 8 edges: groups handle k+g and k+4+g
        int ca = sc[k + g];
        int cb = sc[k + 4 + g];
        uint4 va = seqb4[(unsigned)ca * 16u + j4];
        uint4 vb = seqb4[(unsigned)cb * 16u + j4];
        float ta = f1r + f2[ca];
        float tb = f1r + f2[cb];
        float wa = __expf(fmaxf(ta, ALPHA * ta));   // leaky_relu == max(t, a*t), a<1
        float wb = __expf(fmaxf(tb, ALPHA * tb));
        ss += wa + wb;
        a0 += wa * bflo(va.x); a1 += wa * bfhi(va.x);
        a2 += wa * bflo(va.y); a3 += wa * bfhi(va.y);
        a4 += wa * bflo(va.z); a5 += wa * bfhi(va.z);
        a6 += wa * bflo(va.w); a7 += wa * bfhi(va.w);
        a0 += wb * bflo(vb.x); a1 += wb * bfhi(vb.x);
        a2 += wb * bflo(vb.y); a3 += wb * bfhi(vb.y);
        a4 += wb * bflo(vb.z); a5 += wb * bfhi(vb.z);
        a6 += wb * bflo(vb.w); a7 += wb * bfhi(vb.w);
    }
    for (; k < deg; k += 4) {                // clamped rounds: up to 7 leftover edges
        unsigned int ke = k + g;
        int c = sc[ke < deg ? ke : deg - 1];
        uint4 v = seqb4[(unsigned)c * 16u + j4];
        float t = f1r + f2[c];
        float w = __expf(fmaxf(t, ALPHA * t));
        if (ke >= deg) w = 0.f;
        ss += w;
        a0 += w * bflo(v.x); a1 += w * bfhi(v.x);
        a2 += w * bflo(v.y); a3 += w * bfhi(v.y);
        a4 += w * bflo(v.z); a5 += w * bfhi(v.z);
        a6 += w * bflo(v.w); a7 += w * bfhi(v.w);
    }

    // reduce the 4 edge-groups (lane bits 4,5)
    a0 += __shfl_xor(a0, 16); a0 += __shfl_xor(a0, 32);
    a1 += __shfl_xor(a1, 16); a1 += __shfl_xor(a1, 32);
    a2 += __shfl_xor(a2, 16); a2 += __shfl_xor(a2, 32);
    a3 += __shfl_xor(a3, 16); a3 += __shfl_xor(a3, 32);
    a4 += __shfl_xor(a4, 16); a4 += __shfl_xor(a4, 32);
    a5 += __shfl_xor(a5, 16); a5 += __shfl_xor(a5, 32);
    a6 += __shfl_xor(a6, 16); a6 += __shfl_xor(a6, 32);
    a7 += __shfl_xor(a7, 16); a7 += __shfl_xor(a7, 32);
    ss += __shfl_xor(ss, 16); ss += __shfl_xor(ss, 32);

    if (g == 0) {
        float inv = (deg > 0) ? 1.f / ss : 0.f;   // empty row -> bias only
        float4 b0 = ((const float4*)bias)[j4 * 2];
        float4 b1 = ((const float4*)bias)[j4 * 2 + 1];
        float4* orow = (float4*)(out + (size_t)wid * D_OUT);
        orow[j4 * 2]     = make_float4(a0 * inv + b0.x, a1 * inv + b0.y,
                                       a2 * inv + b0.z, a3 * inv + b0.w);
        orow[j4 * 2 + 1] = make_float4(a4 * inv + b1.x, a5 * inv + b1.y,
                                       a6 * inv + b1.z, a7 * inv + b1.w);
    }
}

extern "C" void kernel_launch(void* const* d_in, const int* in_sizes, int n_in,
                              void* d_out, int out_size, void* d_ws, size_t ws_size,
                              hipStream_t stream) {
    const float* feat = (const float*)d_in[0];
    const int*   row  = (const int*)d_in[1];
    const int*   col  = (const int*)d_in[2];
    const float* W    = (const float*)d_in[3];
    const float* al_w = (const float*)d_in[4];
    const float* al_b = (const float*)d_in[5];
    const float* ar_w = (const float*)d_in[6];
    const float* ar_b = (const float*)d_in[7];
    const float* bias = (const float*)d_in[8];
    float* out = (float*)d_out;

    char* ws = (char*)d_ws;
    size_t off = 0;
    auto carve = [&](size_t bytes) -> void* {
        off = (off + 255) & ~(size_t)255;
        void* p = ws + off;
        off += bytes;
        return p;
    };
    unsigned int* seqb     = (unsigned int*)carve((size_t)N_NODES * 64 * 4);  // bf16x2 packed
    float*        f1       = (float*)       carve((size_t)N_NODES * 4);
    float*        f2       = (float*)       carve((size_t)N_NODES * 4);
    unsigned int* cnt      = (unsigned int*)carve((size_t)N_NODES * 4);
    unsigned int* offs     = (unsigned int*)carve((size_t)N_NODES * 4);
    unsigned int* bsums    = (unsigned int*)carve(1024 * 4);
    unsigned int* bexcl    = (unsigned int*)carve(1024 * 4);
    short*        WT       = (short*)       carve((size_t)D_IN * D_OUT * 2);  // bf16 W^T
    unsigned char* localrank = (unsigned char*)carve((size_t)N_EDGES);
    unsigned int* blockpre = (unsigned int*)carve((size_t)NB_HIST * HWORDS * 4);  // 12.5 MB
    // histpk (12.5 MB) is dead after scanb_kernel; sorted_c (12.8 MB) is written
    // only afterwards (stream-ordered) -> alias them in one region.
    int*          sorted_c = (int*)         carve((size_t)N_EDGES * 4);
    unsigned int* histpk   = (unsigned int*)sorted_c;
    (void)ws_size; (void)in_sizes; (void)n_in; (void)out_size;

    const int nb_nodes = (N_NODES + 255) / 256;     // 391
    const int nb_gemm  = (N_NODES + 63) / 64;       // 1563 (last block guarded)
    const int nb_scanb = (HWORDS + 255) / 256;      // 98
    const int nb_scat  = N_EDGES / 256;             // 12500 exact
    const int nb_row   = N_NODES / 4;               // 25000 exact (4 waves/block)

    wt_kernel<<<(D_IN * D_OUT) / 256, 256, 0, stream>>>(W, WT);
    gemm_kernel<<<nb_gemm, 256, 0, stream>>>(feat, WT, al_w, al_b, ar_w, ar_b, seqb, f1, f2);
    hist_kernel<<<NB_HIST, 1024, 0, stream>>>(row, localrank, histpk);
    scanb_kernel<<<nb_scanb, 256, 0, stream>>>(histpk, blockpre, (uint4*)cnt);
    scan1<<<nb_nodes, 256, 0, stream>>>(cnt, offs, bsums);
    scan2<<<1, 512, 0, stream>>>(bsums, bexcl, nb_nodes);
    scan3<<<nb_nodes, 256, 0, stream>>>(offs, bexcl);
    scatter_kernel<<<nb_scat, 256, 0, stream>>>(row, col, localrank,
                                                (const unsigned char*)blockpre, offs, sorted_c);
    row_kernel<<<nb_row, 256, 0, stream>>>((const uint4*)seqb, sorted_c, offs, cnt, f1, f2, bias, out);
}

// Round 3
// 475.793 us; speedup vs baseline: 1.1872x; 1.0027x over previous
//
#include <hip/hip_runtime.h>
#include <math.h>

#define N_NODES 100000
#define N_EDGES 3200000
#define D_IN    256
#define D_OUT   128
#define ALPHA   0.2f

// counting-sort chunking: per-block LDS-privatized histogram
#define NB_HIST 125                    // chunks == hist blocks
#define CHUNK   (N_EDGES / NB_HIST)    // 25600 edges per chunk (25600 % 1024 == 0)
#define HWORDS  (N_NODES / 4)          // 25000 packed u8x4 bins = 100 KB LDS

typedef short bf8_t  __attribute__((ext_vector_type(8)));   // 8 bf16 (MFMA A/B frag)
typedef float f4_t   __attribute__((ext_vector_type(4)));   // 4 f32  (MFMA C/D frag)

// round-to-nearest-even f32 -> bf16
__device__ __forceinline__ unsigned int f2bf(float x) {
    unsigned int u = __float_as_uint(x);
    return (u + 0x7fffu + ((u >> 16) & 1u)) >> 16;
}
__device__ __forceinline__ unsigned int packbf(float lo, float hi) {
    return f2bf(lo) | (f2bf(hi) << 16);
}
__device__ __forceinline__ float bflo(unsigned int v) { return __uint_as_float(v << 16); }
__device__ __forceinline__ float bfhi(unsigned int v) { return __uint_as_float(v & 0xffff0000u); }

// ---------- WT: W[k][n] f32 -> WT[n][k] bf16 (64 KB, done once per launch) ----------
__global__ void wt_kernel(const float* __restrict__ W, short* __restrict__ WT) {
    int i = blockIdx.x * 256 + threadIdx.x;   // 32768
    int n = i >> 8, k = i & 255;
    WT[i] = (short)f2bf(W[k * 128 + n]);
}

// ---------- GEMM via bf16 MFMA: seq = feat @ W + fused f1/f2 epilogue ----------
// Block: 256 thr = 4 waves; wave handles 16 rows x 128 cols. Block = 64 rows.
// feat tile staged f32->bf16 into LDS ([64][264] shorts, +16B row pad -> fragment
// reads are bank-bandwidth-optimal). B-frags read straight from global WT (16B
// contiguous per lane, L1/L2-resident 64 KB). mfma_f32_16x16x32_bf16:
//   A[m=lane&15][k=quad*8+j], B[k=quad*8+j][n=lane&15], C col=lane&15 row=quad*4+reg.
__global__ __launch_bounds__(256) void gemm_kernel(const float* __restrict__ feat,
                                                   const short* __restrict__ WT,
                                                   const float* __restrict__ al_w,
                                                   const float* __restrict__ al_b,
                                                   const float* __restrict__ ar_w,
                                                   const float* __restrict__ ar_b,
                                                   unsigned int* __restrict__ seqb,
                                                   float* __restrict__ f1,
                                                   float* __restrict__ f2) {
    __shared__ char ldsA[64 * 528];   // 33.8 KB  (row stride 528 B = 264 bf16)
    const int tid = threadIdx.x;
    const int tb  = blockIdx.x * 64;

    // ---- stage feat[tb..tb+63][0..255] as bf16 (clamp rows past N; stores guarded) ----
#pragma unroll
    for (int i = 0; i < 16; i++) {
        int idx = i * 256 + tid;          // over 4096 float4
        int r   = idx >> 6;               // tile row 0..63
        int c4  = idx & 63;               // float4 index 0..63
        int gr  = tb + r; if (gr >= N_NODES) gr = N_NODES - 1;
        float4 v = ((const float4*)feat)[(size_t)gr * 64 + c4];
        *(uint2*)(ldsA + r * 528 + c4 * 8) =
            make_uint2(packbf(v.x, v.y), packbf(v.z, v.w));
    }
    __syncthreads();

    const int w    = tid >> 6;      // wave 0..3 -> rows tb + w*16 ..
    const int lane = tid & 63;
    const int m    = lane & 15;     // A row / B col within tile
    const int q    = lane >> 4;     // quad -> k offset q*8, C rows q*4..q*4+3

    const char*  aptr  = ldsA + (w * 16 + m) * 528 + q * 16;
    const short* bbase = WT + m * 256 + q * 8;   // + nt*16*256 + kc*32

    f4_t acc[8];
#pragma unroll
    for (int nt = 0; nt < 8; nt++) acc[nt] = (f4_t)(0.f);

#pragma unroll
    for (int kc = 0; kc < 8; kc++) {
        bf8_t a = *(const bf8_t*)(aptr + kc * 64);
#pragma unroll
        for (int nt = 0; nt < 8; nt++) {
            bf8_t b = *(const bf8_t*)(bbase + nt * 4096 + kc * 32);
            acc[nt] = __builtin_amdgcn_mfma_f32_16x16x32_bf16(a, b, acc[nt], 0, 0, 0);
        }
    }

    // ---- epilogue 1: seqb packed bf16x2 (pair adjacent cols via shfl_xor(1)) ----
    const int node_base = tb + w * 16 + q * 4;
#pragma unroll
    for (int nt = 0; nt < 8; nt++) {
#pragma unroll
        for (int j = 0; j < 4; j++) {
            float own   = acc[nt][j];
            float other = __shfl_xor(own, 1);
            int node = node_base + j;
            if (!(lane & 1) && node < N_NODES)
                seqb[(size_t)node * 64 + nt * 8 + (m >> 1)] = packbf(own, other);
        }
    }

    // ---- epilogue 2: f1/f2 = seq . al_w / ar_w (reduce over cols = lanes m) ----
    float p1[4] = {0.f, 0.f, 0.f, 0.f}, p2[4] = {0.f, 0.f, 0.f, 0.f};
#pragma unroll
    for (int nt = 0; nt < 8; nt++) {
        float av = al_w[nt * 16 + m];
        float rv = ar_w[nt * 16 + m];
#pragma unroll
        for (int j = 0; j < 4; j++) {
            p1[j] += acc[nt][j] * av;
            p2[j] += acc[nt][j] * rv;
        }
    }
#pragma unroll
    for (int j = 0; j < 4; j++) {
#pragma unroll
        for (int mk = 1; mk < 16; mk <<= 1) {
            p1[j] += __shfl_xor(p1[j], mk);
            p2[j] += __shfl_xor(p2[j], mk);
        }
    }
    if (m == 0) {
        float alb = al_b[0], arb = ar_b[0];
#pragma unroll
        for (int j = 0; j < 4; j++) {
            int node = node_base + j;
            if (node < N_NODES) {
                f1[node] = p1[j] + alb;
                f2[node] = p2[j] + arb;
            }
        }
    }
}

// ---------- chunk-privatized histogram + within-chunk rank (NO global atomics) ----------
// Each block owns one 25600-edge chunk and a full 100K-bin histogram in LDS,
// packed 4 u8 counters per u32 word (degrees are <=255 so bytes never carry).
// LDS atomicAdd's return value IS the edge's within-chunk rank. 1024 threads:
// only 1 block/CU fits (100 KB LDS), so maximize waves per block (16) for MLP.
__global__ __launch_bounds__(1024) void hist_kernel(const int* __restrict__ row,
                                                    unsigned char* __restrict__ localrank,
                                                    unsigned int* __restrict__ histpk) {
    __shared__ unsigned int h[HWORDS];    // 100 KB
    const int tid = threadIdx.x;
    for (int i = tid; i < HWORDS; i += 1024) h[i] = 0u;
    __syncthreads();

    const int base = blockIdx.x * CHUNK;
#pragma unroll 5
    for (int it = 0; it < CHUNK / 1024; it++) {
        int e = base + it * 1024 + tid;
        int r = row[e];
        unsigned int sh  = (unsigned int)(r & 3) * 8u;
        unsigned int old = atomicAdd(&h[r >> 2], 1u << sh);
        localrank[e] = (unsigned char)((old >> sh) & 0xffu);
    }
    __syncthreads();

    unsigned int* dst = histpk + (size_t)blockIdx.x * HWORDS;
    for (int i = tid; i < HWORDS; i += 1024) dst[i] = h[i];
}

// ---------- cross-chunk exclusive prefix per row + total degree ----------
// Thread owns 4 rows (one packed word). Packed byte-adds cannot carry since the
// running total per row is the final degree (<=255). unroll 5 -> 5 loads in flight
// (grid is only 390 waves; latency hiding must come from ILP).
__global__ __launch_bounds__(256) void scanb_kernel(const unsigned int* __restrict__ histpk,
                                                    unsigned int* __restrict__ blockpre,
                                                    uint4* __restrict__ cnt4) {
    int w = blockIdx.x * 256 + threadIdx.x;
    if (w >= HWORDS) return;
    unsigned int run = 0u;
#pragma unroll 5
    for (int b = 0; b < NB_HIST; b++) {
        unsigned int hv = histpk[(size_t)b * HWORDS + w];
        blockpre[(size_t)b * HWORDS + w] = run;
        run += hv;
    }
    cnt4[w] = make_uint4(run & 0xffu, (run >> 8) & 0xffu,
                         (run >> 16) & 0xffu, run >> 24);
}

// ---------- exclusive scan of degrees -> CSR row offsets ----------
__global__ void scan1(const unsigned int* __restrict__ cnt,
                      unsigned int* __restrict__ offs,
                      unsigned int* __restrict__ bsums) {
    __shared__ unsigned int s[256];
    int t = threadIdx.x;
    int i = blockIdx.x * 256 + t;
    unsigned int v = (i < N_NODES) ? cnt[i] : 0u;
    s[t] = v; __syncthreads();
    for (int d = 1; d < 256; d <<= 1) {
        unsigned int x = (t >= d) ? s[t - d] : 0u;
        __syncthreads();
        s[t] += x;
        __syncthreads();
    }
    if (i < N_NODES) offs[i] = s[t] - v;
    if (t == 255) bsums[blockIdx.x] = s[255];
}

__global__ void scan2(const unsigned int* __restrict__ bsums,
                      unsigned int* __restrict__ bexcl, int nb) {
    __shared__ unsigned int s[512];
    int t = threadIdx.x;
    unsigned int v = (t < nb) ? bsums[t] : 0u;
    s[t] = v; __syncthreads();
    for (int d = 1; d < 512; d <<= 1) {
        unsigned int x = (t >= d) ? s[t - d] : 0u;
        __syncthreads();
        s[t] += x;
        __syncthreads();
    }
    if (t < nb) bexcl[t] = s[t] - v;
}

__global__ void scan3(unsigned int* __restrict__ offs,
                      const unsigned int* __restrict__ bexcl) {
    int i = blockIdx.x * 256 + threadIdx.x;
    if (i < N_NODES) offs[i] += bexcl[blockIdx.x];
}

// ---------- persistent CSR scatter: LDS-staged prefix window + nontemporal stores ----
// 2 blocks per chunk (250 blocks x 512 thr). Each block copies its chunk's packed
// blockpre window (100 KB) into LDS ONCE, then streams 12800 edges. Kills the
// per-edge random global byte-gather (was ~a 64 B line pull per edge, re-fetched
// per XCD) and the write-allocate line fills on sorted_c (nt store bypasses L2).
__global__ __launch_bounds__(512) void scatter_kernel(const int* __restrict__ row,
                                                      const int* __restrict__ col,
                                                      const unsigned char* __restrict__ localrank,
                                                      const unsigned int* __restrict__ blockpre,
                                                      const unsigned int* __restrict__ offs,
                                                      int* __restrict__ sorted_c) {
    __shared__ unsigned int wpre[HWORDS];    // 100 KB packed u8x4 prefix window
    const int b    = blockIdx.x >> 1;        // chunk
    const int half = blockIdx.x & 1;
    const int tid  = threadIdx.x;

    const unsigned int* src = blockpre + (size_t)b * HWORDS;
    for (int i = tid; i < HWORDS; i += 512) wpre[i] = src[i];
    __syncthreads();

    const int base = b * CHUNK + half * (CHUNK / 2);
#pragma unroll 5
    for (int it = 0; it < (CHUNK / 2) / 512; it++) {
        int e = base + it * 512 + tid;
        int r = row[e];
        unsigned int bp = (wpre[r >> 2] >> ((unsigned int)(r & 3) * 8u)) & 0xffu;
        unsigned int p  = offs[r] + bp + (unsigned int)localrank[e];
        __builtin_nontemporal_store(col[e], &sorted_c[p]);
    }
}

// ---------- row aggregate ----------
// One wave per row. 16 lanes x uint4 (16 B/lane) cover one 256 B seqb row ->
// 4 edge-groups per wave. Main loop: 16 edges/iter (4 uint4 gathers in flight
// per lane) for memory-level parallelism against L2-miss latency.
__global__ __launch_bounds__(256) void row_kernel(const uint4* __restrict__ seqb4,
                                                  const int* __restrict__ sorted_c,
                                                  const unsigned int* __restrict__ offs,
                                                  const unsigned int* __restrict__ cnt,
                                                  const float* __restrict__ f1,
                                                  const float* __restrict__ f2,
                                                  const float* __restrict__ bias,
                                                  float* __restrict__ out) {
    int wid  = (blockIdx.x * 256 + threadIdx.x) >> 6;   // row
    int lane = threadIdx.x & 63;
    int g    = lane >> 4;        // edge group 0..3
    int j4   = lane & 15;        // uint4 index within row: cols 8*j4 .. 8*j4+7
    if (wid >= N_NODES) return;
    unsigned int start = offs[wid];
    unsigned int deg   = cnt[wid];
    const int* sc = sorted_c + start;
    float f1r = f1[wid];

    float a0 = 0.f, a1 = 0.f, a2 = 0.f, a3 = 0.f;
    float a4 = 0.f, a5 = 0.f, a6 = 0.f, a7 = 0.f, ss = 0.f;

    unsigned int k = 0;
    for (; k + 16 <= deg; k += 16) {         // 16 edges: group g handles k+g+4i
        int c0 = sc[k + g];
        int c1 = sc[k + 4 + g];
        int c2 = sc[k + 8 + g];
        int c3 = sc[k + 12 + g];
        uint4 v0 = seqb4[(unsigned)c0 * 16u + j4];
        uint4 v1 = seqb4[(unsigned)c1 * 16u + j4];
        uint4 v2 = seqb4[(unsigned)c2 * 16u + j4];
        uint4 v3 = seqb4[(unsigned)c3 * 16u + j4];
        float t0 = f1r + f2[c0], t1 = f1r + f2[c1];
        float t2 = f1r + f2[c2], t3 = f1r + f2[c3];
        float w0 = __expf(fmaxf(t0, ALPHA * t0));
        float w1 = __expf(fmaxf(t1, ALPHA * t1));
        float w2 = __expf(fmaxf(t2, ALPHA * t2));
        float w3 = __expf(fmaxf(t3, ALPHA * t3));
        ss += (w0 + w1) + (w2 + w3);
        a0 += w0 * bflo(v0.x); a1 += w0 * bfhi(v0.x);
        a2 += w0 * bflo(v0.y); a3 += w0 * bfhi(v0.y);
        a4 += w0 * bflo(v0.z); a5 += w0 * bfhi(v0.z);
        a6 += w0 * bflo(v0.w); a7 += w0 * bfhi(v0.w);
        a0 += w1 * bflo(v1.x); a1 += w1 * bfhi(v1.x);
        a2 += w1 * bflo(v1.y); a3 += w1 * bfhi(v1.y);
        a4 += w1 * bflo(v1.z); a5 += w1 * bfhi(v1.z);
        a6 += w1 * bflo(v1.w); a7 += w1 * bfhi(v1.w);
        a0 += w2 * bflo(v2.x); a1 += w2 * bfhi(v2.x);
        a2 += w2 * bflo(v2.y); a3 += w2 * bfhi(v2.y);
        a4 += w2 * bflo(v2.z); a5 += w2 * bfhi(v2.z);
        a6 += w2 * bflo(v2.w); a7 += w2 * bfhi(v2.w);
        a0 += w3 * bflo(v3.x); a1 += w3 * bfhi(v3.x);
        a2 += w3 * bflo(v3.y); a3 += w3 * bfhi(v3.y);
        a4 += w3 * bflo(v3.z); a5 += w3 * bfhi(v3.z);
        a6 += w3 * bflo(v3.w); a7 += w3 * bfhi(v3.w);
    }
    for (; k + 8 <= deg; k += 8) {           // 8 edges: groups handle k+g and k+4+g
        int ca = sc[k + g];
        int cb = sc[k + 4 + g];
        uint4 va = seqb4[(unsigned)ca * 16u + j4];
        uint4 vb = seqb4[(unsigned)cb * 16u + j4];
        float ta = f1r + f2[ca];
        float tb = f1r + f2[cb];
        float wa = __expf(fmaxf(ta, ALPHA * ta));
        float wb = __expf(fmaxf(tb, ALPHA * tb));
        ss += wa + wb;
        a0 += wa * bflo(va.x); a1 += wa * bfhi(va.x);
        a2 += wa * bflo(va.y); a3 += wa * bfhi(va.y);
        a4 += wa * bflo(va.z); a5 += wa * bfhi(va.z);
        a6 += wa * bflo(va.w); a7 += wa * bfhi(va.w);
        a0 += wb * bflo(vb.x); a1 += wb * bfhi(vb.x);
        a2 += wb * bflo(vb.y); a3 += wb * bfhi(vb.y);
        a4 += wb * bflo(vb.z); a5 += wb * bfhi(vb.z);
        a6 += wb * bflo(vb.w); a7 += wb * bfhi(vb.w);
    }
    for (; k < deg; k += 4) {                // clamped rounds: up to 7 leftover edges
        unsigned int ke = k + g;
        int c = sc[ke < deg ? ke : deg - 1];
        uint4 v = seqb4[(unsigned)c * 16u + j4];
        float t = f1r + f2[c];
        float w = __expf(fmaxf(t, ALPHA * t));
        if (ke >= deg) w = 0.f;
        ss += w;
        a0 += w * bflo(v.x); a1 += w * bfhi(v.x);
        a2 += w * bflo(v.y); a3 += w * bfhi(v.y);
        a4 += w * bflo(v.z); a5 += w * bfhi(v.z);
        a6 += w * bflo(v.w); a7 += w * bfhi(v.w);
    }

    // reduce the 4 edge-groups (lane bits 4,5)
    a0 += __shfl_xor(a0, 16); a0 += __shfl_xor(a0, 32);
    a1 += __shfl_xor(a1, 16); a1 += __shfl_xor(a1, 32);
    a2 += __shfl_xor(a2, 16); a2 += __shfl_xor(a2, 32);
    a3 += __shfl_xor(a3, 16); a3 += __shfl_xor(a3, 32);
    a4 += __shfl_xor(a4, 16); a4 += __shfl_xor(a4, 32);
    a5 += __shfl_xor(a5, 16); a5 += __shfl_xor(a5, 32);
    a6 += __shfl_xor(a6, 16); a6 += __shfl_xor(a6, 32);
    a7 += __shfl_xor(a7, 16); a7 += __shfl_xor(a7, 32);
    ss += __shfl_xor(ss, 16); ss += __shfl_xor(ss, 32);

    if (g == 0) {
        float inv = (deg > 0) ? 1.f / ss : 0.f;   // empty row -> bias only
        float4 b0 = ((const float4*)bias)[j4 * 2];
        float4 b1 = ((const float4*)bias)[j4 * 2 + 1];
        float4* orow = (float4*)(out + (size_t)wid * D_OUT);
        orow[j4 * 2]     = make_float4(a0 * inv + b0.x, a1 * inv + b0.y,
                                       a2 * inv + b0.z, a3 * inv + b0.w);
        orow[j4 * 2 + 1] = make_float4(a4 * inv + b1.x, a5 * inv + b1.y,
                                       a6 * inv + b1.z, a7 * inv + b1.w);
    }
}

extern "C" void kernel_launch(void* const* d_in, const int* in_sizes, int n_in,
                              void* d_out, int out_size, void* d_ws, size_t ws_size,
                              hipStream_t stream) {
    const float* feat = (const float*)d_in[0];
    const int*   row  = (const int*)d_in[1];
    const int*   col  = (const int*)d_in[2];
    const float* W    = (const float*)d_in[3];
    const float* al_w = (const float*)d_in[4];
    const float* al_b = (const float*)d_in[5];
    const float* ar_w = (const float*)d_in[6];
    const float* ar_b = (const float*)d_in[7];
    const float* bias = (const float*)d_in[8];
    float* out = (float*)d_out;

    char* ws = (char*)d_ws;
    size_t off = 0;
    auto carve = [&](size_t bytes) -> void* {
        off = (off + 255) & ~(size_t)255;
        void* p = ws + off;
        off += bytes;
        return p;
    };
    unsigned int* seqb     = (unsigned int*)carve((size_t)N_NODES * 64 * 4);  // bf16x2 packed
    float*        f1       = (float*)       carve((size_t)N_NODES * 4);
    float*        f2       = (float*)       carve((size_t)N_NODES * 4);
    unsigned int* cnt      = (unsigned int*)carve((size_t)N_NODES * 4);
    unsigned int* offs     = (unsigned int*)carve((size_t)N_NODES * 4);
    unsigned int* bsums    = (unsigned int*)carve(1024 * 4);
    unsigned int* bexcl    = (unsigned int*)carve(1024 * 4);
    short*        WT       = (short*)       carve((size_t)D_IN * D_OUT * 2);  // bf16 W^T
    unsigned char* localrank = (unsigned char*)carve((size_t)N_EDGES);
    unsigned int* blockpre = (unsigned int*)carve((size_t)NB_HIST * HWORDS * 4);  // 12.5 MB
    // histpk (12.5 MB) is dead after scanb_kernel; sorted_c (12.8 MB) is written
    // only afterwards (stream-ordered) -> alias them in one region.
    int*          sorted_c = (int*)         carve((size_t)N_EDGES * 4);
    unsigned int* histpk   = (unsigned int*)sorted_c;
    (void)ws_size; (void)in_sizes; (void)n_in; (void)out_size;

    const int nb_nodes = (N_NODES + 255) / 256;     // 391
    const int nb_gemm  = (N_NODES + 63) / 64;       // 1563 (last block guarded)
    const int nb_scanb = (HWORDS + 255) / 256;      // 98
    const int nb_row   = N_NODES / 4;               // 25000 exact (4 waves/block)

    wt_kernel<<<(D_IN * D_OUT) / 256, 256, 0, stream>>>(W, WT);
    gemm_kernel<<<nb_gemm, 256, 0, stream>>>(feat, WT, al_w, al_b, ar_w, ar_b, seqb, f1, f2);
    hist_kernel<<<NB_HIST, 1024, 0, stream>>>(row, localrank, histpk);
    scanb_kernel<<<nb_scanb, 256, 0, stream>>>(histpk, blockpre, (uint4*)cnt);
    scan1<<<nb_nodes, 256, 0, stream>>>(cnt, offs, bsums);
    scan2<<<1, 512, 0, stream>>>(bsums, bexcl, nb_nodes);
    scan3<<<nb_nodes, 256, 0, stream>>>(offs, bexcl);
    scatter_kernel<<<NB_HIST * 2, 512, 0, stream>>>(row, col, localrank,
                                                    blockpre, offs, sorted_c);
    row_kernel<<<nb_row, 256, 0, stream>>>((const uint4*)seqb, sorted_c, offs, cnt, f1, f2, bias, out);
}

// Round 4
// 450.948 us; speedup vs baseline: 1.2526x; 1.0551x over previous
//
#include <hip/hip_runtime.h>
#include <math.h>

#define N_NODES 100000
#define N_EDGES 3200000
#define D_IN    256
#define D_OUT   128
#define ALPHA   0.2f

// counting-sort chunking: per-block LDS-privatized histogram
#define NB_HIST 125                    // chunks == hist blocks
#define CHUNK   (N_EDGES / NB_HIST)    // 25600 edges per chunk (25600 % 1024 == 0)
#define HWORDS  (N_NODES / 4)          // 25000 packed u8x4 bins = 100 KB LDS
#define NGRP    5                      // chunk groups for parallel scan
#define GLEN    (NB_HIST / NGRP)       // 25 chunks per group

typedef short bf8_t  __attribute__((ext_vector_type(8)));   // 8 bf16 (MFMA A/B frag)
typedef float f4_t   __attribute__((ext_vector_type(4)));   // 4 f32  (MFMA C/D frag)

// round-to-nearest-even f32 -> bf16
__device__ __forceinline__ unsigned int f2bf(float x) {
    unsigned int u = __float_as_uint(x);
    return (u + 0x7fffu + ((u >> 16) & 1u)) >> 16;
}
__device__ __forceinline__ unsigned int packbf(float lo, float hi) {
    return f2bf(lo) | (f2bf(hi) << 16);
}
__device__ __forceinline__ float bflo(unsigned int v) { return __uint_as_float(v << 16); }
__device__ __forceinline__ float bfhi(unsigned int v) { return __uint_as_float(v & 0xffff0000u); }

// ---------- WTs: W[k][n] f32 -> bf16 in MFMA FRAGMENT order ----------
// Fragment (kc,nt) occupies a contiguous 1 KB block: lane l's 8 bf16 at l*16 B.
// Element j of lane (q*16+m) = B[k=kc*32+q*8+j][n=nt*16+m]. This makes every
// B-frag load in gemm a single wave-coalesced 1 KB read (16 sequential lines)
// instead of a 64-distinct-line gather (512 B lane stride) -> ~4x fewer L1
// transactions on the gemm hot loop.
__global__ void wt_kernel(const float* __restrict__ W, short* __restrict__ WTs) {
    int o = blockIdx.x * 256 + threadIdx.x;   // 32768
    int j    = o & 7;
    int lane = (o >> 3) & 63;
    int nt   = (o >> 9) & 7;
    int kc   = o >> 12;
    int n = nt * 16 + (lane & 15);
    int k = kc * 32 + (lane >> 4) * 8 + j;
    WTs[o] = (short)f2bf(W[k * 128 + n]);
}

// ---------- GEMM via bf16 MFMA: seq = feat @ W + fused f1/f2 epilogue ----------
// Block: 256 thr = 4 waves; wave handles 16 rows x 128 cols. Block = 64 rows.
// feat tile staged f32->bf16 into LDS ([64][264] shorts, +16B row pad). B-frags
// read from global WTs in fragment order (coalesced 1 KB per instruction,
// 64 KB stream per wave, L1/L2-resident). mfma_f32_16x16x32_bf16:
//   A[m=lane&15][k=quad*8+j], B[k=quad*8+j][n=lane&15], C col=lane&15 row=quad*4+reg.
__global__ __launch_bounds__(256) void gemm_kernel(const float* __restrict__ feat,
                                                   const short* __restrict__ WTs,
                                                   const float* __restrict__ al_w,
                                                   const float* __restrict__ al_b,
                                                   const float* __restrict__ ar_w,
                                                   const float* __restrict__ ar_b,
                                                   unsigned int* __restrict__ seqb,
                                                   float* __restrict__ f1,
                                                   float* __restrict__ f2) {
    __shared__ char ldsA[64 * 528];   // 33.8 KB  (row stride 528 B = 264 bf16)
    const int tid = threadIdx.x;
    const int tb  = blockIdx.x * 64;

    // ---- stage feat[tb..tb+63][0..255] as bf16 (clamp rows past N) ----
#pragma unroll
    for (int i = 0; i < 16; i++) {
        int idx = i * 256 + tid;          // over 4096 float4
        int r   = idx >> 6;               // tile row 0..63
        int c4  = idx & 63;               // float4 index 0..63
        int gr  = tb + r; if (gr >= N_NODES) gr = N_NODES - 1;
        float4 v = ((const float4*)feat)[(size_t)gr * 64 + c4];
        *(uint2*)(ldsA + r * 528 + c4 * 8) =
            make_uint2(packbf(v.x, v.y), packbf(v.z, v.w));
    }
    __syncthreads();

    const int w    = tid >> 6;      // wave 0..3 -> rows tb + w*16 ..
    const int lane = tid & 63;
    const int m    = lane & 15;     // A row / B col within tile
    const int q    = lane >> 4;     // quad -> k offset q*8, C rows q*4..q*4+3

    const char*  aptr = ldsA + (w * 16 + m) * 528 + q * 16;
    const short* bb   = WTs + (size_t)lane * 8;   // + (kc*8+nt)*512 shorts

    f4_t acc[8];
#pragma unroll
    for (int nt = 0; nt < 8; nt++) acc[nt] = (f4_t)(0.f);

#pragma unroll
    for (int kc = 0; kc < 8; kc++) {
        bf8_t a = *(const bf8_t*)(aptr + kc * 64);
#pragma unroll
        for (int nt = 0; nt < 8; nt++) {
            bf8_t b = *(const bf8_t*)(bb + (kc * 8 + nt) * 512);
            acc[nt] = __builtin_amdgcn_mfma_f32_16x16x32_bf16(a, b, acc[nt], 0, 0, 0);
        }
    }

    // ---- epilogue 1: seqb packed bf16x2 (pair adjacent cols via shfl_xor(1)) ----
    const int node_base = tb + w * 16 + q * 4;
#pragma unroll
    for (int nt = 0; nt < 8; nt++) {
#pragma unroll
        for (int j = 0; j < 4; j++) {
            float own   = acc[nt][j];
            float other = __shfl_xor(own, 1);
            int node = node_base + j;
            if (!(lane & 1) && node < N_NODES)
                seqb[(size_t)node * 64 + nt * 8 + (m >> 1)] = packbf(own, other);
        }
    }

    // ---- epilogue 2: f1/f2 = seq . al_w / ar_w (reduce over cols = lanes m) ----
    float p1[4] = {0.f, 0.f, 0.f, 0.f}, p2[4] = {0.f, 0.f, 0.f, 0.f};
#pragma unroll
    for (int nt = 0; nt < 8; nt++) {
        float av = al_w[nt * 16 + m];
        float rv = ar_w[nt * 16 + m];
#pragma unroll
        for (int j = 0; j < 4; j++) {
            p1[j] += acc[nt][j] * av;
            p2[j] += acc[nt][j] * rv;
        }
    }
#pragma unroll
    for (int j = 0; j < 4; j++) {
#pragma unroll
        for (int mk = 1; mk < 16; mk <<= 1) {
            p1[j] += __shfl_xor(p1[j], mk);
            p2[j] += __shfl_xor(p2[j], mk);
        }
    }
    if (m == 0) {
        float alb = al_b[0], arb = ar_b[0];
#pragma unroll
        for (int j = 0; j < 4; j++) {
            int node = node_base + j;
            if (node < N_NODES) {
                f1[node] = p1[j] + alb;
                f2[node] = p2[j] + arb;
            }
        }
    }
}

// ---------- chunk-privatized histogram + within-chunk rank (NO global atomics) ----------
// Each block owns one 25600-edge chunk and a full 100K-bin histogram in LDS,
// packed 4 u8 counters per u32 word (degrees are <=255 so bytes never carry).
// LDS atomicAdd's return value IS the edge's within-chunk rank. Full unroll:
// all 25 row-loads in flight per thread.
__global__ __launch_bounds__(1024) void hist_kernel(const int* __restrict__ row,
                                                    unsigned char* __restrict__ localrank,
                                                    unsigned int* __restrict__ histpk) {
    __shared__ unsigned int h[HWORDS];    // 100 KB
    const int tid = threadIdx.x;
    for (int i = tid; i < HWORDS; i += 1024) h[i] = 0u;
    __syncthreads();

    const int base = blockIdx.x * CHUNK;
#pragma unroll
    for (int it = 0; it < CHUNK / 1024; it++) {
        int e = base + it * 1024 + tid;
        int r = row[e];
        unsigned int sh  = (unsigned int)(r & 3) * 8u;
        unsigned int old = atomicAdd(&h[r >> 2], 1u << sh);
        localrank[e] = (unsigned char)((old >> sh) & 0xffu);
    }
    __syncthreads();

    unsigned int* dst = histpk + (size_t)blockIdx.x * HWORDS;
    for (int i = tid; i < HWORDS; i += 1024) dst[i] = h[i];
}

// ---------- cross-chunk prefix, phase A: 5 parallel groups of 25 chunks ----------
// Thread (g,w): serial exclusive scan over its group's 25 chunks; blockpre gets
// the GROUP-RELATIVE prefix (<=255, bytes can't carry); gsum gets the group total.
// 5x the waves of the old single-pass scanb (125k threads vs 25k).
__global__ __launch_bounds__(256) void scanbA_kernel(const unsigned int* __restrict__ histpk,
                                                     unsigned int* __restrict__ blockpre,
                                                     unsigned int* __restrict__ gsum) {
    int id = blockIdx.x * 256 + threadIdx.x;
    if (id >= NGRP * HWORDS) return;
    int g = id / HWORDS;
    int w = id - g * HWORDS;
    const unsigned int* hp = histpk   + (size_t)(g * GLEN) * HWORDS + w;
    unsigned int*       bp = blockpre + (size_t)(g * GLEN) * HWORDS + w;
    unsigned int run = 0u;
#pragma unroll 5
    for (int i = 0; i < GLEN; i++) {
        unsigned int hv = hp[(size_t)i * HWORDS];
        bp[(size_t)i * HWORDS] = run;
        run += hv;
    }
    gsum[(size_t)g * HWORDS + w] = run;
}

// ---------- phase B: scan the 5 group sums (in-place -> exclusive group base) ----
__global__ __launch_bounds__(256) void scanbB_kernel(unsigned int* __restrict__ gsum,
                                                     uint4* __restrict__ cnt4) {
    int w = blockIdx.x * 256 + threadIdx.x;
    if (w >= HWORDS) return;
    unsigned int run = 0u;
#pragma unroll
    for (int g = 0; g < NGRP; g++) {
        unsigned int v = gsum[(size_t)g * HWORDS + w];
        gsum[(size_t)g * HWORDS + w] = run;     // exclusive base, packed u8x4
        run += v;                                // byte-wise, total = deg <= 255
    }
    cnt4[w] = make_uint4(run & 0xffu, (run >> 8) & 0xffu,
                         (run >> 16) & 0xffu, run >> 24);
}

// ---------- exclusive scan of degrees -> CSR row offsets ----------
__global__ void scan1(const unsigned int* __restrict__ cnt,
                      unsigned int* __restrict__ offs,
                      unsigned int* __restrict__ bsums) {
    __shared__ unsigned int s[256];
    int t = threadIdx.x;
    int i = blockIdx.x * 256 + t;
    unsigned int v = (i < N_NODES) ? cnt[i] : 0u;
    s[t] = v; __syncthreads();
    for (int d = 1; d < 256; d <<= 1) {
        unsigned int x = (t >= d) ? s[t - d] : 0u;
        __syncthreads();
        s[t] += x;
        __syncthreads();
    }
    if (i < N_NODES) offs[i] = s[t] - v;
    if (t == 255) bsums[blockIdx.x] = s[255];
}

__global__ void scan2(const unsigned int* __restrict__ bsums,
                      unsigned int* __restrict__ bexcl, int nb) {
    __shared__ unsigned int s[512];
    int t = threadIdx.x;
    unsigned int v = (t < nb) ? bsums[t] : 0u;
    s[t] = v; __syncthreads();
    for (int d = 1; d < 512; d <<= 1) {
        unsigned int x = (t >= d) ? s[t - d] : 0u;
        __syncthreads();
        s[t] += x;
        __syncthreads();
    }
    if (t < nb) bexcl[t] = s[t] - v;
}

__global__ void scan3(unsigned int* __restrict__ offs,
                      const unsigned int* __restrict__ bexcl) {
    int i = blockIdx.x * 256 + threadIdx.x;
    if (i < N_NODES) offs[i] += bexcl[blockIdx.x];
}

// ---------- offs_g[g][r] = offs[r] + group-base(g,r): scatter reads ONE gather ----
__global__ __launch_bounds__(256) void offsg_kernel(const unsigned int* __restrict__ offs,
                                                    const unsigned int* __restrict__ gsum,
                                                    unsigned int* __restrict__ offs_g) {
    int id = blockIdx.x * 256 + threadIdx.x;
    if (id >= NGRP * HWORDS) return;
    int g = id / HWORDS;
    int w = id - g * HWORDS;
    unsigned int gb = gsum[(size_t)g * HWORDS + w];
    uint4 o4 = *(const uint4*)(offs + w * 4);
    uint4 r;
    r.x = o4.x + (gb & 0xffu);
    r.y = o4.y + ((gb >> 8) & 0xffu);
    r.z = o4.z + ((gb >> 16) & 0xffu);
    r.w = o4.w + (gb >> 24);
    ((uint4*)(offs_g + (size_t)g * N_NODES))[w] = r;
}

// ---------- persistent CSR scatter: LDS-staged prefix window + nontemporal stores ----
// 2 blocks per chunk (250 blocks x 512 thr). Each block copies its chunk's packed
// blockpre window (100 KB) into LDS ONCE, then streams 12800 edges.
// position = offs_g[group][r] + within-group-chunk-prefix + within-chunk rank.
__global__ __launch_bounds__(512) void scatter_kernel(const int* __restrict__ row,
                                                      const int* __restrict__ col,
                                                      const unsigned char* __restrict__ localrank,
                                                      const unsigned int* __restrict__ blockpre,
                                                      const unsigned int* __restrict__ offs_g,
                                                      int* __restrict__ sorted_c) {
    __shared__ unsigned int wpre[HWORDS];    // 100 KB packed u8x4 prefix window
    const int b    = blockIdx.x >> 1;        // chunk
    const int half = blockIdx.x & 1;
    const int tid  = threadIdx.x;

    const unsigned int* src = blockpre + (size_t)b * HWORDS;
    for (int i = tid; i < HWORDS; i += 512) wpre[i] = src[i];
    __syncthreads();

    const unsigned int* og = offs_g + (size_t)(b / GLEN) * N_NODES;
    const int base = b * CHUNK + half * (CHUNK / 2);
#pragma unroll 5
    for (int it = 0; it < (CHUNK / 2) / 512; it++) {
        int e = base + it * 512 + tid;
        int r = row[e];
        unsigned int bp = (wpre[r >> 2] >> ((unsigned int)(r & 3) * 8u)) & 0xffu;
        unsigned int p  = og[r] + bp + (unsigned int)localrank[e];
        __builtin_nontemporal_store(col[e], &sorted_c[p]);
    }
}

// ---------- row aggregate ----------
// One wave per row. 16 lanes x uint4 (16 B/lane) cover one 256 B seqb row ->
// 4 edge-groups per wave. Main loop: 16 edges/iter (4 uint4 gathers in flight
// per lane) for memory-level parallelism against L2-miss latency.
__global__ __launch_bounds__(256) void row_kernel(const uint4* __restrict__ seqb4,
                                                  const int* __restrict__ sorted_c,
                                                  const unsigned int* __restrict__ offs,
                                                  const unsigned int* __restrict__ cnt,
                                                  const float* __restrict__ f1,
                                                  const float* __restrict__ f2,
                                                  const float* __restrict__ bias,
                                                  float* __restrict__ out) {
    int wid  = (blockIdx.x * 256 + threadIdx.x) >> 6;   // row
    int lane = threadIdx.x & 63;
    int g    = lane >> 4;        // edge group 0..3
    int j4   = lane & 15;        // uint4 index within row: cols 8*j4 .. 8*j4+7
    if (wid >= N_NODES) return;
    unsigned int start = offs[wid];
    unsigned int deg   = cnt[wid];
    const int* sc = sorted_c + start;
    float f1r = f1[wid];

    float a0 = 0.f, a1 = 0.f, a2 = 0.f, a3 = 0.f;
    float a4 = 0.f, a5 = 0.f, a6 = 0.f, a7 = 0.f, ss = 0.f;

    unsigned int k = 0;
    for (; k + 16 <= deg; k += 16) {         // 16 edges: group g handles k+g+4i
        int c0 = sc[k + g];
        int c1 = sc[k + 4 + g];
        int c2 = sc[k + 8 + g];
        int c3 = sc[k + 12 + g];
        uint4 v0 = seqb4[(unsigned)c0 * 16u + j4];
        uint4 v1 = seqb4[(unsigned)c1 * 16u + j4];
        uint4 v2 = seqb4[(unsigned)c2 * 16u + j4];
        uint4 v3 = seqb4[(unsigned)c3 * 16u + j4];
        float t0 = f1r + f2[c0], t1 = f1r + f2[c1];
        float t2 = f1r + f2[c2], t3 = f1r + f2[c3];
        float w0 = __expf(fmaxf(t0, ALPHA * t0));
        float w1 = __expf(fmaxf(t1, ALPHA * t1));
        float w2 = __expf(fmaxf(t2, ALPHA * t2));
        float w3 = __expf(fmaxf(t3, ALPHA * t3));
        ss += (w0 + w1) + (w2 + w3);
        a0 += w0 * bflo(v0.x); a1 += w0 * bfhi(v0.x);
        a2 += w0 * bflo(v0.y); a3 += w0 * bfhi(v0.y);
        a4 += w0 * bflo(v0.z); a5 += w0 * bfhi(v0.z);
        a6 += w0 * bflo(v0.w); a7 += w0 * bfhi(v0.w);
        a0 += w1 * bflo(v1.x); a1 += w1 * bfhi(v1.x);
        a2 += w1 * bflo(v1.y); a3 += w1 * bfhi(v1.y);
        a4 += w1 * bflo(v1.z); a5 += w1 * bfhi(v1.z);
        a6 += w1 * bflo(v1.w); a7 += w1 * bfhi(v1.w);
        a0 += w2 * bflo(v2.x); a1 += w2 * bfhi(v2.x);
        a2 += w2 * bflo(v2.y); a3 += w2 * bfhi(v2.y);
        a4 += w2 * bflo(v2.z); a5 += w2 * bfhi(v2.z);
        a6 += w2 * bflo(v2.w); a7 += w2 * bfhi(v2.w);
        a0 += w3 * bflo(v3.x); a1 += w3 * bfhi(v3.x);
        a2 += w3 * bflo(v3.y); a3 += w3 * bfhi(v3.y);
        a4 += w3 * bflo(v3.z); a5 += w3 * bfhi(v3.z);
        a6 += w3 * bflo(v3.w); a7 += w3 * bfhi(v3.w);
    }
    for (; k + 8 <= deg; k += 8) {           // 8 edges: groups handle k+g and k+4+g
        int ca = sc[k + g];
        int cb = sc[k + 4 + g];
        uint4 va = seqb4[(unsigned)ca * 16u + j4];
        uint4 vb = seqb4[(unsigned)cb * 16u + j4];
        float ta = f1r + f2[ca];
        float tb = f1r + f2[cb];
        float wa = __expf(fmaxf(ta, ALPHA * ta));
        float wb = __expf(fmaxf(tb, ALPHA * tb));
        ss += wa + wb;
        a0 += wa * bflo(va.x); a1 += wa * bfhi(va.x);
        a2 += wa * bflo(va.y); a3 += wa * bfhi(va.y);
        a4 += wa * bflo(va.z); a5 += wa * bfhi(va.z);
        a6 += wa * bflo(va.w); a7 += wa * bfhi(va.w);
        a0 += wb * bflo(vb.x); a1 += wb * bfhi(vb.x);
        a2 += wb * bflo(vb.y); a3 += wb * bfhi(vb.y);
        a4 += wb * bflo(vb.z); a5 += wb * bfhi(vb.z);
        a6 += wb * bflo(vb.w); a7 += wb * bfhi(vb.w);
    }
    for (; k < deg; k += 4) {                // clamped rounds: up to 7 leftover edges
        unsigned int ke = k + g;
        int c = sc[ke < deg ? ke : deg - 1];
        uint4 v = seqb4[(unsigned)c * 16u + j4];
        float t = f1r + f2[c];
        float w = __expf(fmaxf(t, ALPHA * t));
        if (ke >= deg) w = 0.f;
        ss += w;
        a0 += w * bflo(v.x); a1 += w * bfhi(v.x);
        a2 += w * bflo(v.y); a3 += w * bfhi(v.y);
        a4 += w * bflo(v.z); a5 += w * bfhi(v.z);
        a6 += w * bflo(v.w); a7 += w * bfhi(v.w);
    }

    // reduce the 4 edge-groups (lane bits 4,5)
    a0 += __shfl_xor(a0, 16); a0 += __shfl_xor(a0, 32);
    a1 += __shfl_xor(a1, 16); a1 += __shfl_xor(a1, 32);
    a2 += __shfl_xor(a2, 16); a2 += __shfl_xor(a2, 32);
    a3 += __shfl_xor(a3, 16); a3 += __shfl_xor(a3, 32);
    a4 += __shfl_xor(a4, 16); a4 += __shfl_xor(a4, 32);
    a5 += __shfl_xor(a5, 16); a5 += __shfl_xor(a5, 32);
    a6 += __shfl_xor(a6, 16); a6 += __shfl_xor(a6, 32);
    a7 += __shfl_xor(a7, 16); a7 += __shfl_xor(a7, 32);
    ss += __shfl_xor(ss, 16); ss += __shfl_xor(ss, 32);

    if (g == 0) {
        float inv = (deg > 0) ? 1.f / ss : 0.f;   // empty row -> bias only
        float4 b0 = ((const float4*)bias)[j4 * 2];
        float4 b1 = ((const float4*)bias)[j4 * 2 + 1];
        float4* orow = (float4*)(out + (size_t)wid * D_OUT);
        orow[j4 * 2]     = make_float4(a0 * inv + b0.x, a1 * inv + b0.y,
                                       a2 * inv + b0.z, a3 * inv + b0.w);
        orow[j4 * 2 + 1] = make_float4(a4 * inv + b1.x, a5 * inv + b1.y,
                                       a6 * inv + b1.z, a7 * inv + b1.w);
    }
}

extern "C" void kernel_launch(void* const* d_in, const int* in_sizes, int n_in,
                              void* d_out, int out_size, void* d_ws, size_t ws_size,
                              hipStream_t stream) {
    const float* feat = (const float*)d_in[0];
    const int*   row  = (const int*)d_in[1];
    const int*   col  = (const int*)d_in[2];
    const float* W    = (const float*)d_in[3];
    const float* al_w = (const float*)d_in[4];
    const float* al_b = (const float*)d_in[5];
    const float* ar_w = (const float*)d_in[6];
    const float* ar_b = (const float*)d_in[7];
    const float* bias = (const float*)d_in[8];
    float* out = (float*)d_out;

    char* ws = (char*)d_ws;
    size_t off = 0;
    auto carve = [&](size_t bytes) -> void* {
        off = (off + 255) & ~(size_t)255;
        void* p = ws + off;
        off += bytes;
        return p;
    };
    unsigned int* seqb     = (unsigned int*)carve((size_t)N_NODES * 64 * 4);  // bf16x2 packed
    float*        f1       = (float*)       carve((size_t)N_NODES * 4);
    float*        f2       = (float*)       carve((size_t)N_NODES * 4);
    unsigned int* cnt      = (unsigned int*)carve((size_t)N_NODES * 4);
    unsigned int* offs     = (unsigned int*)carve((size_t)N_NODES * 4);
    unsigned int* bsums    = (unsigned int*)carve(1024 * 4);
    unsigned int* bexcl    = (unsigned int*)carve(1024 * 4);
    short*        WTs      = (short*)       carve((size_t)D_IN * D_OUT * 2);  // bf16 W frag-order
    unsigned char* localrank = (unsigned char*)carve((size_t)N_EDGES);
    unsigned int* blockpre = (unsigned int*)carve((size_t)NB_HIST * HWORDS * 4);  // 12.5 MB
    unsigned int* gsum     = (unsigned int*)carve((size_t)NGRP * HWORDS * 4);     // 0.5 MB
    unsigned int* offs_g   = (unsigned int*)carve((size_t)NGRP * N_NODES * 4);    // 2 MB
    // histpk (12.5 MB) is dead after scanbA; sorted_c (12.8 MB) is written
    // only afterwards (stream-ordered) -> alias them in one region.
    int*          sorted_c = (int*)         carve((size_t)N_EDGES * 4);
    unsigned int* histpk   = (unsigned int*)sorted_c;
    (void)ws_size; (void)in_sizes; (void)n_in; (void)out_size;

    const int nb_nodes = (N_NODES + 255) / 256;      // 391
    const int nb_gemm  = (N_NODES + 63) / 64;        // 1563 (last block guarded)
    const int nb_gw    = (NGRP * HWORDS + 255) / 256;// 489
    const int nb_row   = N_NODES / 4;                // 25000 exact (4 waves/block)

    wt_kernel<<<(D_IN * D_OUT) / 256, 256, 0, stream>>>(W, WTs);
    gemm_kernel<<<nb_gemm, 256, 0, stream>>>(feat, WTs, al_w, al_b, ar_w, ar_b, seqb, f1, f2);
    hist_kernel<<<NB_HIST, 1024, 0, stream>>>(row, localrank, histpk);
    scanbA_kernel<<<nb_gw, 256, 0, stream>>>(histpk, blockpre, gsum);
    scanbB_kernel<<<(HWORDS + 255) / 256, 256, 0, stream>>>(gsum, (uint4*)cnt);
    scan1<<<nb_nodes, 256, 0, stream>>>(cnt, offs, bsums);
    scan2<<<1, 512, 0, stream>>>(bsums, bexcl, nb_nodes);
    scan3<<<nb_nodes, 256, 0, stream>>>(offs, bexcl);
    offsg_kernel<<<nb_gw, 256, 0, stream>>>(offs, gsum, offs_g);
    scatter_kernel<<<NB_HIST * 2, 512, 0, stream>>>(row, col, localrank,
                                                    blockpre, offs_g, sorted_c);
    row_kernel<<<nb_row, 256, 0, stream>>>((const uint4*)seqb, sorted_c, offs, cnt, f1, f2, bias, out);
}

// Round 5
// 446.722 us; speedup vs baseline: 1.2644x; 1.0095x over previous
//
#include <hip/hip_runtime.h>
#include <math.h>

#define N_NODES 100000
#define N_EDGES 3200000
#define D_IN    256
#define D_OUT   128
#define ALPHA   0.2f

// counting-sort chunking: per-block LDS-privatized histogram
#define NB_HIST 125                    // chunks == hist blocks
#define CHUNK   (N_EDGES / NB_HIST)    // 25600 edges per chunk (25600 % 1024 == 0)
#define HWORDS  (N_NODES / 4)          // 25000 packed u8x4 bins = 100 KB LDS
#define NGRP    5                      // chunk groups for parallel scan
#define GLEN    (NB_HIST / NGRP)       // 25 chunks per group

typedef short bf8_t  __attribute__((ext_vector_type(8)));   // 8 bf16 (MFMA A/B frag)
typedef float f4_t   __attribute__((ext_vector_type(4)));   // 4 f32  (MFMA C/D frag)

// round-to-nearest-even f32 -> bf16
__device__ __forceinline__ unsigned int f2bf(float x) {
    unsigned int u = __float_as_uint(x);
    return (u + 0x7fffu + ((u >> 16) & 1u)) >> 16;
}
__device__ __forceinline__ unsigned int packbf(float lo, float hi) {
    return f2bf(lo) | (f2bf(hi) << 16);
}
__device__ __forceinline__ float bflo(unsigned int v) { return __uint_as_float(v << 16); }
__device__ __forceinline__ float bfhi(unsigned int v) { return __uint_as_float(v & 0xffff0000u); }

// ---------- WTs: W[k][n] f32 -> bf16 in MFMA FRAGMENT order ----------
__global__ void wt_kernel(const float* __restrict__ W, short* __restrict__ WTs) {
    int o = blockIdx.x * 256 + threadIdx.x;   // 32768
    int j    = o & 7;
    int lane = (o >> 3) & 63;
    int nt   = (o >> 9) & 7;
    int kc   = o >> 12;
    int n = nt * 16 + (lane & 15);
    int k = kc * 32 + (lane >> 4) * 8 + j;
    WTs[o] = (short)f2bf(W[k * 128 + n]);
}

// ---------- GEMM via bf16 MFMA: seq = feat @ W + fused f1/f2 epilogue ----------
__global__ __launch_bounds__(256) void gemm_kernel(const float* __restrict__ feat,
                                                   const short* __restrict__ WTs,
                                                   const float* __restrict__ al_w,
                                                   const float* __restrict__ al_b,
                                                   const float* __restrict__ ar_w,
                                                   const float* __restrict__ ar_b,
                                                   unsigned int* __restrict__ seqb,
                                                   float* __restrict__ f1,
                                                   float* __restrict__ f2) {
    __shared__ char ldsA[64 * 528];   // 33.8 KB  (row stride 528 B = 264 bf16)
    const int tid = threadIdx.x;
    const int tb  = blockIdx.x * 64;

#pragma unroll
    for (int i = 0; i < 16; i++) {
        int idx = i * 256 + tid;          // over 4096 float4
        int r   = idx >> 6;               // tile row 0..63
        int c4  = idx & 63;               // float4 index 0..63
        int gr  = tb + r; if (gr >= N_NODES) gr = N_NODES - 1;
        float4 v = ((const float4*)feat)[(size_t)gr * 64 + c4];
        *(uint2*)(ldsA + r * 528 + c4 * 8) =
            make_uint2(packbf(v.x, v.y), packbf(v.z, v.w));
    }
    __syncthreads();

    const int w    = tid >> 6;      // wave 0..3 -> rows tb + w*16 ..
    const int lane = tid & 63;
    const int m    = lane & 15;     // A row / B col within tile
    const int q    = lane >> 4;     // quad -> k offset q*8, C rows q*4..q*4+3

    const char*  aptr = ldsA + (w * 16 + m) * 528 + q * 16;
    const short* bb   = WTs + (size_t)lane * 8;   // + (kc*8+nt)*512 shorts

    f4_t acc[8];
#pragma unroll
    for (int nt = 0; nt < 8; nt++) acc[nt] = (f4_t)(0.f);

#pragma unroll
    for (int kc = 0; kc < 8; kc++) {
        bf8_t a = *(const bf8_t*)(aptr + kc * 64);
#pragma unroll
        for (int nt = 0; nt < 8; nt++) {
            bf8_t b = *(const bf8_t*)(bb + (kc * 8 + nt) * 512);
            acc[nt] = __builtin_amdgcn_mfma_f32_16x16x32_bf16(a, b, acc[nt], 0, 0, 0);
        }
    }

    // ---- epilogue 1: seqb packed bf16x2 (pair adjacent cols via shfl_xor(1)) ----
    const int node_base = tb + w * 16 + q * 4;
#pragma unroll
    for (int nt = 0; nt < 8; nt++) {
#pragma unroll
        for (int j = 0; j < 4; j++) {
            float own   = acc[nt][j];
            float other = __shfl_xor(own, 1);
            int node = node_base + j;
            if (!(lane & 1) && node < N_NODES)
                seqb[(size_t)node * 64 + nt * 8 + (m >> 1)] = packbf(own, other);
        }
    }

    // ---- epilogue 2: f1/f2 = seq . al_w / ar_w (reduce over cols = lanes m) ----
    float p1[4] = {0.f, 0.f, 0.f, 0.f}, p2[4] = {0.f, 0.f, 0.f, 0.f};
#pragma unroll
    for (int nt = 0; nt < 8; nt++) {
        float av = al_w[nt * 16 + m];
        float rv = ar_w[nt * 16 + m];
#pragma unroll
        for (int j = 0; j < 4; j++) {
            p1[j] += acc[nt][j] * av;
            p2[j] += acc[nt][j] * rv;
        }
    }
#pragma unroll
    for (int j = 0; j < 4; j++) {
#pragma unroll
        for (int mk = 1; mk < 16; mk <<= 1) {
            p1[j] += __shfl_xor(p1[j], mk);
            p2[j] += __shfl_xor(p2[j], mk);
        }
    }
    if (m == 0) {
        float alb = al_b[0], arb = ar_b[0];
#pragma unroll
        for (int j = 0; j < 4; j++) {
            int node = node_base + j;
            if (node < N_NODES) {
                f1[node] = p1[j] + alb;
                f2[node] = p2[j] + arb;
            }
        }
    }
}

// ---------- chunk-privatized histogram + within-chunk rank (NO global atomics) ----------
__global__ __launch_bounds__(1024) void hist_kernel(const int* __restrict__ row,
                                                    unsigned char* __restrict__ localrank,
                                                    unsigned int* __restrict__ histpk) {
    __shared__ unsigned int h[HWORDS];    // 100 KB
    const int tid = threadIdx.x;
    for (int i = tid; i < HWORDS; i += 1024) h[i] = 0u;
    __syncthreads();

    const int base = blockIdx.x * CHUNK;
#pragma unroll
    for (int it = 0; it < CHUNK / 1024; it++) {
        int e = base + it * 1024 + tid;
        int r = row[e];
        unsigned int sh  = (unsigned int)(r & 3) * 8u;
        unsigned int old = atomicAdd(&h[r >> 2], 1u << sh);
        localrank[e] = (unsigned char)((old >> sh) & 0xffu);
    }
    __syncthreads();

    unsigned int* dst = histpk + (size_t)blockIdx.x * HWORDS;
    for (int i = tid; i < HWORDS; i += 1024) dst[i] = h[i];
}

// ---------- cross-chunk prefix, phase A: 5 parallel groups of 25 chunks ----------
__global__ __launch_bounds__(256) void scanbA_kernel(const unsigned int* __restrict__ histpk,
                                                     unsigned int* __restrict__ blockpre,
                                                     unsigned int* __restrict__ gsum) {
    int id = blockIdx.x * 256 + threadIdx.x;
    if (id >= NGRP * HWORDS) return;
    int g = id / HWORDS;
    int w = id - g * HWORDS;
    const unsigned int* hp = histpk   + (size_t)(g * GLEN) * HWORDS + w;
    unsigned int*       bp = blockpre + (size_t)(g * GLEN) * HWORDS + w;
    unsigned int run = 0u;
#pragma unroll 5
    for (int i = 0; i < GLEN; i++) {
        unsigned int hv = hp[(size_t)i * HWORDS];
        bp[(size_t)i * HWORDS] = run;
        run += hv;
    }
    gsum[(size_t)g * HWORDS + w] = run;
}

// ---------- fused: group-sum scan (-> bases in gsum, cnt) + node-degree block scan ----
// Block = 256 threads = 1024 nodes. Thread w owns 4 packed nodes. Produces offs
// (block-local exclusive) + bsums[block] for the 98-block top scan.
__global__ __launch_bounds__(256) void degscan_kernel(unsigned int* __restrict__ gsum,
                                                      uint4* __restrict__ cnt4,
                                                      unsigned int* __restrict__ offs,
                                                      unsigned int* __restrict__ bsums) {
    __shared__ unsigned int s[256];
    const int t = threadIdx.x;
    const int w = blockIdx.x * 256 + t;
    unsigned int run = 0u, T = 0u;
    unsigned int d0 = 0, d1 = 0, d2 = 0;
    if (w < HWORDS) {
#pragma unroll
        for (int g = 0; g < NGRP; g++) {
            unsigned int v = gsum[(size_t)g * HWORDS + w];
            gsum[(size_t)g * HWORDS + w] = run;     // exclusive group base (packed u8x4)
            run += v;                                // byte-wise; totals <= 255
        }
        cnt4[w] = make_uint4(run & 0xffu, (run >> 8) & 0xffu,
                             (run >> 16) & 0xffu, run >> 24);
        d0 = run & 0xffu; d1 = (run >> 8) & 0xffu; d2 = (run >> 16) & 0xffu;
        T = d0 + d1 + d2 + (run >> 24);
    }
    s[t] = T; __syncthreads();
    for (int d = 1; d < 256; d <<= 1) {
        unsigned int x = (t >= d) ? s[t - d] : 0u;
        __syncthreads();
        s[t] += x;
        __syncthreads();
    }
    if (w < HWORDS) {
        unsigned int excl = s[t] - T;
        offs[w * 4 + 0] = excl;
        offs[w * 4 + 1] = excl + d0;
        offs[w * 4 + 2] = excl + d0 + d1;
        offs[w * 4 + 3] = excl + d0 + d1 + d2;
    }
    if (t == 255) bsums[blockIdx.x] = s[255];
}

__global__ void scan2(const unsigned int* __restrict__ bsums,
                      unsigned int* __restrict__ bexcl, int nb) {
    __shared__ unsigned int s[512];
    int t = threadIdx.x;
    unsigned int v = (t < nb) ? bsums[t] : 0u;
    s[t] = v; __syncthreads();
    for (int d = 1; d < 512; d <<= 1) {
        unsigned int x = (t >= d) ? s[t - d] : 0u;
        __syncthreads();
        s[t] += x;
        __syncthreads();
    }
    if (t < nb) bexcl[t] = s[t] - v;
}

// ---------- fused: offs += block base; offs_g[g][i] = offs[i] + group base ----------
__global__ __launch_bounds__(256) void scan3g_kernel(unsigned int* __restrict__ offs,
                                                     const unsigned int* __restrict__ bexcl,
                                                     const unsigned int* __restrict__ gsum,
                                                     unsigned int* __restrict__ offs_g) {
    int i = blockIdx.x * 256 + threadIdx.x;
    if (i >= N_NODES) return;
    unsigned int o = offs[i] + bexcl[i >> 10];   // 1024 nodes per degscan block
    offs[i] = o;
    unsigned int sh = (unsigned int)(i & 3) * 8u;
#pragma unroll
    for (int g = 0; g < NGRP; g++) {
        unsigned int gb = (gsum[(size_t)g * HWORDS + (i >> 2)] >> sh) & 0xffu;
        offs_g[(size_t)g * N_NODES + i] = o + gb;
    }
}

// ---------- persistent CSR scatter: LDS-staged prefix window, PLAIN stores ----------
// (nt store reverted: it defeated L2 write-combining on 3.2M random 4 B stores and
// evicted sorted_c right before row_kernel re-reads it.)
__global__ __launch_bounds__(512) void scatter_kernel(const int* __restrict__ row,
                                                      const int* __restrict__ col,
                                                      const unsigned char* __restrict__ localrank,
                                                      const unsigned int* __restrict__ blockpre,
                                                      const unsigned int* __restrict__ offs_g,
                                                      int* __restrict__ sorted_c) {
    __shared__ unsigned int wpre[HWORDS];    // 100 KB packed u8x4 prefix window
    const int b    = blockIdx.x >> 1;        // chunk
    const int half = blockIdx.x & 1;
    const int tid  = threadIdx.x;

    const unsigned int* src = blockpre + (size_t)b * HWORDS;
    for (int i = tid; i < HWORDS; i += 512) wpre[i] = src[i];
    __syncthreads();

    const unsigned int* og = offs_g + (size_t)(b / GLEN) * N_NODES;
    const int base = b * CHUNK + half * (CHUNK / 2);
#pragma unroll 5
    for (int it = 0; it < (CHUNK / 2) / 512; it++) {
        int e = base + it * 512 + tid;
        int r = row[e];
        unsigned int bp = (wpre[r >> 2] >> ((unsigned int)(r & 3) * 8u)) & 0xffu;
        unsigned int p  = og[r] + bp + (unsigned int)localrank[e];
        sorted_c[p] = col[e];
    }
}

// ---------- row aggregate (split into two half-grids for profiler visibility) ----------
__device__ __forceinline__ void row_body(int wid_base,
                                         const uint4* __restrict__ seqb4,
                                         const int* __restrict__ sorted_c,
                                         const unsigned int* __restrict__ offs,
                                         const unsigned int* __restrict__ cnt,
                                         const float* __restrict__ f1,
                                         const float* __restrict__ f2,
                                         const float* __restrict__ bias,
                                         float* __restrict__ out) {
    int wid  = wid_base + ((blockIdx.x * 256 + threadIdx.x) >> 6);
    int lane = threadIdx.x & 63;
    int g    = lane >> 4;        // edge group 0..3
    int j4   = lane & 15;        // uint4 index within row: cols 8*j4 .. 8*j4+7
    unsigned int start = offs[wid];
    unsigned int deg   = cnt[wid];
    const int* sc = sorted_c + start;
    float f1r = f1[wid];

    float a0 = 0.f, a1 = 0.f, a2 = 0.f, a3 = 0.f;
    float a4 = 0.f, a5 = 0.f, a6 = 0.f, a7 = 0.f, ss = 0.f;

    unsigned int k = 0;
    for (; k + 16 <= deg; k += 16) {         // 16 edges: group g handles k+g+4i
        int c0 = sc[k + g];
        int c1 = sc[k + 4 + g];
        int c2 = sc[k + 8 + g];
        int c3 = sc[k + 12 + g];
        uint4 v0 = seqb4[(unsigned)c0 * 16u + j4];
        uint4 v1 = seqb4[(unsigned)c1 * 16u + j4];
        uint4 v2 = seqb4[(unsigned)c2 * 16u + j4];
        uint4 v3 = seqb4[(unsigned)c3 * 16u + j4];
        float t0 = f1r + f2[c0], t1 = f1r + f2[c1];
        float t2 = f1r + f2[c2], t3 = f1r + f2[c3];
        float w0 = __expf(fmaxf(t0, ALPHA * t0));
        float w1 = __expf(fmaxf(t1, ALPHA * t1));
        float w2 = __expf(fmaxf(t2, ALPHA * t2));
        float w3 = __expf(fmaxf(t3, ALPHA * t3));
        ss += (w0 + w1) + (w2 + w3);
        a0 += w0 * bflo(v0.x); a1 += w0 * bfhi(v0.x);
        a2 += w0 * bflo(v0.y); a3 += w0 * bfhi(v0.y);
        a4 += w0 * bflo(v0.z); a5 += w0 * bfhi(v0.z);
        a6 += w0 * bflo(v0.w); a7 += w0 * bfhi(v0.w);
        a0 += w1 * bflo(v1.x); a1 += w1 * bfhi(v1.x);
        a2 += w1 * bflo(v1.y); a3 += w1 * bfhi(v1.y);
        a4 += w1 * bflo(v1.z); a5 += w1 * bfhi(v1.z);
        a6 += w1 * bflo(v1.w); a7 += w1 * bfhi(v1.w);
        a0 += w2 * bflo(v2.x); a1 += w2 * bfhi(v2.x);
        a2 += w2 * bflo(v2.y); a3 += w2 * bfhi(v2.y);
        a4 += w2 * bflo(v2.z); a5 += w2 * bfhi(v2.z);
        a6 += w2 * bflo(v2.w); a7 += w2 * bfhi(v2.w);
        a0 += w3 * bflo(v3.x); a1 += w3 * bfhi(v3.x);
        a2 += w3 * bflo(v3.y); a3 += w3 * bfhi(v3.y);
        a4 += w3 * bflo(v3.z); a5 += w3 * bfhi(v3.z);
        a6 += w3 * bflo(v3.w); a7 += w3 * bfhi(v3.w);
    }
    for (; k + 8 <= deg; k += 8) {
        int ca = sc[k + g];
        int cb = sc[k + 4 + g];
        uint4 va = seqb4[(unsigned)ca * 16u + j4];
        uint4 vb = seqb4[(unsigned)cb * 16u + j4];
        float ta = f1r + f2[ca];
        float tb = f1r + f2[cb];
        float wa = __expf(fmaxf(ta, ALPHA * ta));
        float wb = __expf(fmaxf(tb, ALPHA * tb));
        ss += wa + wb;
        a0 += wa * bflo(va.x); a1 += wa * bfhi(va.x);
        a2 += wa * bflo(va.y); a3 += wa * bfhi(va.y);
        a4 += wa * bflo(va.z); a5 += wa * bfhi(va.z);
        a6 += wa * bflo(va.w); a7 += wa * bfhi(va.w);
        a0 += wb * bflo(vb.x); a1 += wb * bfhi(vb.x);
        a2 += wb * bflo(vb.y); a3 += wb * bfhi(vb.y);
        a4 += wb * bflo(vb.z); a5 += wb * bfhi(vb.z);
        a6 += wb * bflo(vb.w); a7 += wb * bfhi(vb.w);
    }
    for (; k < deg; k += 4) {
        unsigned int ke = k + g;
        int c = sc[ke < deg ? ke : deg - 1];
        uint4 v = seqb4[(unsigned)c * 16u + j4];
        float t = f1r + f2[c];
        float w = __expf(fmaxf(t, ALPHA * t));
        if (ke >= deg) w = 0.f;
        ss += w;
        a0 += w * bflo(v.x); a1 += w * bfhi(v.x);
        a2 += w * bflo(v.y); a3 += w * bfhi(v.y);
        a4 += w * bflo(v.z); a5 += w * bfhi(v.z);
        a6 += w * bflo(v.w); a7 += w * bfhi(v.w);
    }

    a0 += __shfl_xor(a0, 16); a0 += __shfl_xor(a0, 32);
    a1 += __shfl_xor(a1, 16); a1 += __shfl_xor(a1, 32);
    a2 += __shfl_xor(a2, 16); a2 += __shfl_xor(a2, 32);
    a3 += __shfl_xor(a3, 16); a3 += __shfl_xor(a3, 32);
    a4 += __shfl_xor(a4, 16); a4 += __shfl_xor(a4, 32);
    a5 += __shfl_xor(a5, 16); a5 += __shfl_xor(a5, 32);
    a6 += __shfl_xor(a6, 16); a6 += __shfl_xor(a6, 32);
    a7 += __shfl_xor(a7, 16); a7 += __shfl_xor(a7, 32);
    ss += __shfl_xor(ss, 16); ss += __shfl_xor(ss, 32);

    if (g == 0) {
        float inv = (deg > 0) ? 1.f / ss : 0.f;   // empty row -> bias only
        float4 b0 = ((const float4*)bias)[j4 * 2];
        float4 b1 = ((const float4*)bias)[j4 * 2 + 1];
        float4* orow = (float4*)(out + (size_t)wid * D_OUT);
        orow[j4 * 2]     = make_float4(a0 * inv + b0.x, a1 * inv + b0.y,
                                       a2 * inv + b0.z, a3 * inv + b0.w);
        orow[j4 * 2 + 1] = make_float4(a4 * inv + b1.x, a5 * inv + b1.y,
                                       a6 * inv + b1.z, a7 * inv + b1.w);
    }
}

__global__ __launch_bounds__(256) void rowA_kernel(const uint4* __restrict__ seqb4,
                                                   const int* __restrict__ sorted_c,
                                                   const unsigned int* __restrict__ offs,
                                                   const unsigned int* __restrict__ cnt,
                                                   const float* __restrict__ f1,
                                                   const float* __restrict__ f2,
                                                   const float* __restrict__ bias,
                                                   float* __restrict__ out) {
    row_body(0, seqb4, sorted_c, offs, cnt, f1, f2, bias, out);
}
__global__ __launch_bounds__(256) void rowB_kernel(const uint4* __restrict__ seqb4,
                                                   const int* __restrict__ sorted_c,
                                                   const unsigned int* __restrict__ offs,
                                                   const unsigned int* __restrict__ cnt,
                                                   const float* __restrict__ f1,
                                                   const float* __restrict__ f2,
                                                   const float* __restrict__ bias,
                                                   float* __restrict__ out) {
    row_body(N_NODES / 2, seqb4, sorted_c, offs, cnt, f1, f2, bias, out);
}

extern "C" void kernel_launch(void* const* d_in, const int* in_sizes, int n_in,
                              void* d_out, int out_size, void* d_ws, size_t ws_size,
                              hipStream_t stream) {
    const float* feat = (const float*)d_in[0];
    const int*   row  = (const int*)d_in[1];
    const int*   col  = (const int*)d_in[2];
    const float* W    = (const float*)d_in[3];
    const float* al_w = (const float*)d_in[4];
    const float* al_b = (const float*)d_in[5];
    const float* ar_w = (const float*)d_in[6];
    const float* ar_b = (const float*)d_in[7];
    const float* bias = (const float*)d_in[8];
    float* out = (float*)d_out;

    char* ws = (char*)d_ws;
    size_t off = 0;
    auto carve = [&](size_t bytes) -> void* {
        off = (off + 255) & ~(size_t)255;
        void* p = ws + off;
        off += bytes;
        return p;
    };
    unsigned int* seqb     = (unsigned int*)carve((size_t)N_NODES * 64 * 4);  // bf16x2 packed
    float*        f1       = (float*)       carve((size_t)N_NODES * 4);
    float*        f2       = (float*)       carve((size_t)N_NODES * 4);
    unsigned int* cnt      = (unsigned int*)carve((size_t)N_NODES * 4);
    unsigned int* offs     = (unsigned int*)carve((size_t)N_NODES * 4);
    unsigned int* bsums    = (unsigned int*)carve(1024 * 4);
    unsigned int* bexcl    = (unsigned int*)carve(1024 * 4);
    short*        WTs      = (short*)       carve((size_t)D_IN * D_OUT * 2);  // bf16 W frag-order
    unsigned char* localrank = (unsigned char*)carve((size_t)N_EDGES);
    unsigned int* blockpre = (unsigned int*)carve((size_t)NB_HIST * HWORDS * 4);  // 12.5 MB
    unsigned int* gsum     = (unsigned int*)carve((size_t)NGRP * HWORDS * 4);     // 0.5 MB
    unsigned int* offs_g   = (unsigned int*)carve((size_t)NGRP * N_NODES * 4);    // 2 MB
    // histpk (12.5 MB) is dead after scanbA; sorted_c (12.8 MB) is written
    // only afterwards (stream-ordered) -> alias them in one region.
    int*          sorted_c = (int*)         carve((size_t)N_EDGES * 4);
    unsigned int* histpk   = (unsigned int*)sorted_c;
    (void)ws_size; (void)in_sizes; (void)n_in; (void)out_size;

    const int nb_nodes = (N_NODES + 255) / 256;       // 391
    const int nb_gemm  = (N_NODES + 63) / 64;         // 1563 (last block guarded)
    const int nb_gw    = (NGRP * HWORDS + 255) / 256; // 489
    const int nb_deg   = (HWORDS + 255) / 256;        // 98
    const int nb_rowh  = (N_NODES / 2) / 4;           // 12500 (4 waves/block, exact)

    wt_kernel<<<(D_IN * D_OUT) / 256, 256, 0, stream>>>(W, WTs);
    gemm_kernel<<<nb_gemm, 256, 0, stream>>>(feat, WTs, al_w, al_b, ar_w, ar_b, seqb, f1, f2);
    hist_kernel<<<NB_HIST, 1024, 0, stream>>>(row, localrank, histpk);
    scanbA_kernel<<<nb_gw, 256, 0, stream>>>(histpk, blockpre, gsum);
    degscan_kernel<<<nb_deg, 256, 0, stream>>>(gsum, (uint4*)cnt, offs, bsums);
    scan2<<<1, 512, 0, stream>>>(bsums, bexcl, nb_deg);
    scan3g_kernel<<<nb_nodes, 256, 0, stream>>>(offs, bexcl, gsum, offs_g);
    scatter_kernel<<<NB_HIST * 2, 512, 0, stream>>>(row, col, localrank,
                                                    blockpre, offs_g, sorted_c);
    rowA_kernel<<<nb_rowh, 256, 0, stream>>>((const uint4*)seqb, sorted_c, offs, cnt, f1, f2, bias, out);
    rowB_kernel<<<nb_rowh, 256, 0, stream>>>((const uint4*)seqb, sorted_c, offs, cnt, f1, f2, bias, out);
}